// Round 16
// baseline (627.968 us; speedup 1.0000x reference)
//
#include <hip/hip_runtime.h>
#include <hip/hip_bf16.h>
#include <math.h>

#define PI_F 3.14159265358979323846f

static constexpr int F = 128;
static constexpr int KB = 30;
static constexpr int LAYERS = 3;
static constexpr float CUT = 4.0f;
static constexpr int BINS = 512;
static constexpr int ROWW = 768;   // packed row stride in shorts: 128 lanes * 6

typedef short bf16x8 __attribute__((ext_vector_type(8)));
typedef float f32x4 __attribute__((ext_vector_type(4)));

struct __attribute__((packed, aligned(4))) U6 { unsigned int w0, w1, w2; };

__device__ __forceinline__ float bf2f(unsigned short u) {
    union { unsigned int i; float f; } c; c.i = ((unsigned int)u) << 16; return c.f;
}
__device__ __forceinline__ float blo(unsigned int w) {
    union { unsigned int i; float f; } c; c.i = w << 16; return c.f;
}
__device__ __forceinline__ float bhi(unsigned int w) {
    union { unsigned int i; float f; } c; c.i = w & 0xffff0000u; return c.f;
}
__device__ __forceinline__ short f2bf(float x) {
    union { float f; unsigned int u; } c; c.f = x;
    unsigned int r = c.u + 0x7FFFu + ((c.u >> 16) & 1u);
    return (short)(r >> 16);
}

__device__ __forceinline__ float edge_dist(const float* __restrict__ sxyz,
                                           const float* __restrict__ dxyz,
                                           const float* __restrict__ disp,
                                           const float* __restrict__ cell,
                                           int s, int d, int e, float* dx) {
    const float* dp = disp + 3 * (size_t)e;
#pragma unroll
    for (int i = 0; i < 3; i++) {
        float dc = dp[0] * cell[0 * 3 + i] + dp[1] * cell[1 * 3 + i] + dp[2] * cell[2 * 3 + i];
        dx[i] = dxyz[3 * d + i] - (sxyz[3 * s + i] + dc);
    }
    return sqrtf(dx[0] * dx[0] + dx[1] * dx[1] + dx[2] * dx[2]);
}

// ---------------- CSR build (cutoff-filtered) ----------------
__global__ void k_count(const int* __restrict__ edges, const float* __restrict__ sxyz,
                        const float* __restrict__ dxyz, const float* __restrict__ disp,
                        const float* __restrict__ cell, int* __restrict__ cnt, int E) {
    int i = blockIdx.x * blockDim.x + threadIdx.x;
    if (i >= E) return;
    int s = edges[2 * i], d = edges[2 * i + 1];
    float dx[3];
    float dist = edge_dist(sxyz, dxyz, disp, cell, s, d, i, dx);
    if (dist < CUT) atomicAdd(&cnt[d], 1);
}

__global__ void k_scan(const int* __restrict__ cnt, int* __restrict__ off, int n) {
    __shared__ int part[1024];
    int t = threadIdx.x;
    int chunk = (n + 1023) / 1024;
    int b = t * chunk; if (b > n) b = n;
    int e = b + chunk; if (e > n) e = n;
    int s = 0;
    for (int i = b; i < e; i++) s += cnt[i];
    part[t] = s;
    __syncthreads();
    for (int o = 1; o < 1024; o <<= 1) {
        int v = part[t];
        int add = (t >= o) ? part[t - o] : 0;
        __syncthreads();
        part[t] = v + add;
        __syncthreads();
    }
    int run = (t == 0) ? 0 : part[t - 1];
    for (int i = b; i < e; i++) { off[i] = run; run += cnt[i]; }
    if (t == 1023) off[n] = part[1023];
}

__global__ void k_scatter(const int* __restrict__ edges, const float* __restrict__ sxyz,
                          const float* __restrict__ dxyz, const float* __restrict__ disp,
                          const float* __restrict__ cell, int* __restrict__ cur,
                          int* __restrict__ eids, int E) {
    int i = blockIdx.x * blockDim.x + threadIdx.x;
    if (i >= E) return;
    int s = edges[2 * i], d = edges[2 * i + 1];
    float dx[3];
    float dist = edge_dist(sxyz, dxyz, disp, cell, s, d, i, dx);
    if (dist < CUT) {
        int pos = atomicAdd(&cur[d], 1);
        eids[pos] = i;
    }
}

// ---------------- edge records, CSR-ordered ----------------
__global__ void k_geom_rec(const float* __restrict__ sxyz, const float* __restrict__ dxyz,
                           const float* __restrict__ disp, const float* __restrict__ cell,
                           const int* __restrict__ edges, const int* __restrict__ eids,
                           const int* __restrict__ eoff, int ndst,
                           float4* __restrict__ erec, int* __restrict__ srcs) {
    int pos = blockIdx.x * blockDim.x + threadIdx.x;
    if (pos >= eoff[ndst]) return;
    int e = eids[pos];
    int s = edges[2 * e], d = edges[2 * e + 1];
    float dx[3];
    float dist = edge_dist(sxyz, dxyz, disp, cell, s, d, e, dx);
    float inv = 1.0f / fmaxf(dist, 1e-12f);
    float db = fminf(dist * ((float)BINS / CUT), (float)BINS - 0.0001f);
    erec[pos] = make_float4(dx[0] * inv, dx[1] * inv, dx[2] * inv, db);
    srcs[pos] = s;
}

// ---------------- S' basis ----------------
__global__ void k_sbuild(float* __restrict__ Sp) {
    int i = blockIdx.x * blockDim.x + threadIdx.x;
    if (i > BINS) return;
    float d = (float)i * (CUT / (float)BINS);
    float cc = (d < CUT) ? 0.5f * (cosf(PI_F * d / CUT) + 1.0f) : 0.0f;
    float* row = Sp + (size_t)i * 32;
#pragma unroll
    for (int k = 0; k < KB; k++) {
        float kk = (float)(k + 1);
        float st = (d > 1e-12f) ? sinf(PI_F * d * kk / CUT) / d : PI_F * kk / CUT;
        row[k] = cc * st;
    }
    row[30] = cc;
    row[31] = 0.f;
}

// ---------------- assemble fw' ----------------
__global__ void k_fwpack(const float* __restrict__ ai_fw, const float* __restrict__ ai_fb,
                         const float* __restrict__ pm_fw, const float* __restrict__ pm_fb,
                         float* __restrict__ fwp) {
    int i = blockIdx.x * blockDim.x + threadIdx.x;
    if (i >= 6 * 32 * 384) return;
    int tbl = i / (32 * 384);
    int k = (i / 384) % 32;
    int c = i % 384;
    const float* fw = (tbl < 3) ? ai_fw + (size_t)tbl * KB * 384 : pm_fw + (size_t)(tbl - 3) * KB * 384;
    const float* fb = (tbl < 3) ? ai_fb + (size_t)tbl * 384 : pm_fb + (size_t)(tbl - 3) * 384;
    float v = 0.f;
    if (k < KB) v = fw[(size_t)k * 384 + c];
    else if (k == 30) v = fb[c];
    fwp[i] = v;
}

// ---------------- interleave table pairs -> packed 6-short rows ----------------
__global__ void k_tpack(const short* __restrict__ Tbf, short* __restrict__ Tp) {
    int i = blockIdx.x * blockDim.x + threadIdx.x;
    if (i >= 6 * BINS * 128) return;
    int tbl = i / (BINS * 128);
    int rem = i % (BINS * 128);
    int bin = rem >> 7, lane = rem & 127;
    const short* a = Tbf + ((size_t)tbl * (BINS + 1) + bin) * 512 + lane * 4;
    const short* b = a + 512;
    short* o = Tp + ((size_t)tbl * BINS + bin) * ROWW + lane * 6;
    o[0] = a[0]; o[1] = a[1]; o[2] = a[2];
    o[3] = b[0]; o[4] = b[1]; o[5] = b[2];
}

// ---------------- weight transpose+cvt ----------------
struct CvtArgs {
    const float* src[14];
    int dstoff[14];
    int Kk[14];
    int Nn[14];
};
__global__ __launch_bounds__(256) void k_cvtw(CvtArgs a, short* __restrict__ dst) {
    int arr = blockIdx.y, l = blockIdx.z;
    int K = a.Kk[arr], N = a.Nn[arr];
    int tilesx = N / 32, tilesy = K / 32;
    int tile = blockIdx.x;
    if (tile >= tilesx * tilesy) return;
    int tn = (tile % tilesx) * 32, tk = (tile / tilesx) * 32;
    __shared__ float tb[32][33];
    int tx = threadIdx.x & 31, ty = threadIdx.x >> 5;
    const float* src = a.src[arr] + (size_t)l * K * N;
    short* d = dst + a.dstoff[arr] + (size_t)l * K * N;
#pragma unroll
    for (int r = 0; r < 4; r++)
        tb[ty * 4 + r][tx] = src[(size_t)(tk + ty * 4 + r) * N + tn + tx];
    __syncthreads();
#pragma unroll
    for (int r = 0; r < 4; r++)
        d[(size_t)(tn + ty * 4 + r) * K + tk + tx] = f2bf(tb[tx][ty * 4 + r]);
}

// ---------------- init ----------------
__global__ void k_embed(const int* __restrict__ Z, const float* __restrict__ emb,
                        float* __restrict__ s, short* __restrict__ sbf, int n) {
    int i = blockIdx.x * blockDim.x + threadIdx.x;
    if (i < n * F) {
        float v = emb[(size_t)Z[i / F] * F + (i % F)];
        s[i] = v; sbf[i] = f2bf(v);
    }
}

// ---------------- f32 VALU GEMM (table build only) ----------------
__global__ __launch_bounds__(256) void k_gemm(const float* __restrict__ A, const float* __restrict__ B,
                                              void* __restrict__ Cout,
                                              int M, int N, int K, int outmode,
                                              int bstride, int cstride) {
    __shared__ float As[16][64];
    __shared__ float Bs[16][64];
    const float* Bz = B + (size_t)blockIdx.z * bstride;
    int tid = threadIdx.x;
    int bm = blockIdx.y * 64, bn = blockIdx.x * 64;
    int tx = tid & 15, ty = tid >> 4;
    float acc[4][4] = {};
    int arow = tid >> 2;
    int acol = (tid & 3) * 4;
    int brow = tid >> 4;
    int bcol = (tid & 15) * 4;
    for (int k0 = 0; k0 < K; k0 += 16) {
        float4 av = make_float4(0.f, 0.f, 0.f, 0.f);
        int gm = bm + arow;
        if (gm < M) av = *reinterpret_cast<const float4*>(A + (size_t)gm * K + k0 + acol);
        As[acol + 0][arow] = av.x; As[acol + 1][arow] = av.y;
        As[acol + 2][arow] = av.z; As[acol + 3][arow] = av.w;
        float4 bv = *reinterpret_cast<const float4*>(Bz + (size_t)(k0 + brow) * N + bn + bcol);
        Bs[brow][bcol + 0] = bv.x; Bs[brow][bcol + 1] = bv.y;
        Bs[brow][bcol + 2] = bv.z; Bs[brow][bcol + 3] = bv.w;
        __syncthreads();
#pragma unroll
        for (int k = 0; k < 16; k++) {
            float a0 = As[k][ty * 4 + 0], a1 = As[k][ty * 4 + 1];
            float a2 = As[k][ty * 4 + 2], a3 = As[k][ty * 4 + 3];
            float b0 = Bs[k][tx * 4 + 0], b1 = Bs[k][tx * 4 + 1];
            float b2 = Bs[k][tx * 4 + 2], b3 = Bs[k][tx * 4 + 3];
            acc[0][0] += a0 * b0; acc[0][1] += a0 * b1; acc[0][2] += a0 * b2; acc[0][3] += a0 * b3;
            acc[1][0] += a1 * b0; acc[1][1] += a1 * b1; acc[1][2] += a1 * b2; acc[1][3] += a1 * b3;
            acc[2][0] += a2 * b0; acc[2][1] += a2 * b1; acc[2][2] += a2 * b2; acc[2][3] += a2 * b3;
            acc[3][0] += a3 * b0; acc[3][1] += a3 * b1; acc[3][2] += a3 * b2; acc[3][3] += a3 * b3;
        }
        __syncthreads();
    }
#pragma unroll
    for (int i = 0; i < 4; i++) {
        int gm = bm + ty * 4 + i;
        if (gm >= M) continue;
#pragma unroll
        for (int j = 0; j < 4; j++) {
            int gn = bn + tx * 4 + j;
            float v = acc[i][j];
            if (outmode == 0) ((float*)Cout)[(size_t)gm * N + gn] = v;
            else ((short*)Cout)[(size_t)blockIdx.z * cstride + (size_t)gm * 512 + (gn & 127) * 4 + (gn >> 7)] = f2bf(v);
        }
    }
}

// ======== templated MFMA wave-tile helpers ========
template<int RF>
__device__ __forceinline__ void mfma_g(
    const short* __restrict__ A, int arows, int Astride, int row0,
    const short* __restrict__ Bt, int Bstride, int col0, int K,
    int lane, f32x4 acc[RF][4]) {
    const int l15 = lane & 15, l16 = lane >> 4;
    for (int k0 = 0; k0 < K; k0 += 32) {
        const int kbase = k0 + l16 * 8;
        bf16x8 af[RF], bfr[4];
#pragma unroll
        for (int i = 0; i < RF; i++) {
            int r = row0 + i * 16 + l15;
            bf16x8 t = {};
            if (r < arows) t = *reinterpret_cast<const bf16x8*>(A + (size_t)r * Astride + kbase);
            af[i] = t;
        }
#pragma unroll
        for (int j = 0; j < 4; j++)
            bfr[j] = *reinterpret_cast<const bf16x8*>(Bt + (size_t)(col0 + j * 16 + l15) * Bstride + kbase);
#pragma unroll
        for (int i = 0; i < RF; i++)
#pragma unroll
            for (int j = 0; j < 4; j++)
                acc[i][j] = __builtin_amdgcn_mfma_f32_16x16x32_bf16(af[i], bfr[j], acc[i][j], 0, 0, 0);
    }
}
template<int RF>
__device__ __forceinline__ void mfma_l(
    const short* __restrict__ Alds, int Astride, int lrow0,
    const short* __restrict__ Bt, int Bstride, int col0, int K,
    int lane, f32x4 acc[RF][4]) {
    const int l15 = lane & 15, l16 = lane >> 4;
    for (int k0 = 0; k0 < K; k0 += 32) {
        const int kbase = k0 + l16 * 8;
        bf16x8 af[RF], bfr[4];
#pragma unroll
        for (int i = 0; i < RF; i++)
            af[i] = *reinterpret_cast<const bf16x8*>(Alds + (size_t)(lrow0 + i * 16 + l15) * Astride + kbase);
#pragma unroll
        for (int j = 0; j < 4; j++)
            bfr[j] = *reinterpret_cast<const bf16x8*>(Bt + (size_t)(col0 + j * 16 + l15) * Bstride + kbase);
#pragma unroll
        for (int i = 0; i < RF; i++)
#pragma unroll
            for (int j = 0; j < 4; j++)
                acc[i][j] = __builtin_amdgcn_mfma_f32_16x16x32_bf16(af[i], bfr[j], acc[i][j], 0, 0, 0);
    }
}

// ---------------- fused MLP2, 32-row tiles (atom-side) ----------------
__global__ __launch_bounds__(512) void k_mlp2(
    const short* __restrict__ X, const short* __restrict__ w1t, const float* __restrict__ b1,
    const short* __restrict__ w2t, const float* __restrict__ b2,
    short* __restrict__ PV, int M,
    long xzs, long w1zs, long b1zs, long w2zs, long b2zs, long pvzs) {
    __shared__ short hL[32][136];
    const int z = blockIdx.z;
    const int wave = threadIdx.x >> 6, lane = threadIdx.x & 63;
    const int l15 = lane & 15, l16 = lane >> 4;
    const int rows0 = blockIdx.x * 32;
    const short* Xz = X + (size_t)z * xzs;
    if (wave < 4) {
        const int rowblk = wave & 1, colh = wave >> 1;
        f32x4 acc[1][4] = {};
        mfma_g<1>(Xz, M, 128, rows0 + rowblk * 16, w1t + (size_t)z * w1zs, 128, colh * 64, 128, lane, acc);
        const float* b1z = b1 + (size_t)z * b1zs;
#pragma unroll
        for (int j = 0; j < 4; j++) {
            int cn = colh * 64 + j * 16 + l15;
            float bb = b1z[cn];
#pragma unroll
            for (int r = 0; r < 4; r++) {
                float v = acc[0][j][r] + bb;
                v = v / (1.0f + expf(-v));
                hL[rowblk * 16 + l16 * 4 + r][cn] = f2bf(v);
            }
        }
    }
    __syncthreads();
    short* PVz = PV + (size_t)z * pvzs;
    const float* b2z = b2 + (size_t)z * b2zs;
    for (int task = wave; task < 12; task += 8) {
        const int rowblk = task & 1, colb = task >> 1;
        f32x4 acc[1][4] = {};
        mfma_l<1>(&hL[0][0], 136, rowblk * 16, w2t + (size_t)z * w2zs, 128, colb * 64, 128, lane, acc);
#pragma unroll
        for (int j = 0; j < 4; j++) {
            int gn = colb * 64 + j * 16 + l15;
            float bb = b2z[gn];
#pragma unroll
            for (int r = 0; r < 4; r++) {
                int gm = rows0 + rowblk * 16 + l16 * 4 + r;
                if (gm < M)
                    PVz[(size_t)gm * ROWW + (gn & 127) * 6 + (gn >> 7)] = f2bf(acc[0][j][r] + bb);
            }
        }
    }
}

// ---------------- fused atom PaiNN update, 32-row tiles ----------------
__global__ __launch_bounds__(512) void k_paiupd(
    const short* __restrict__ Avv,
    const float* __restrict__ s_in,
    const float* __restrict__ v_in,
    const short* __restrict__ Ut, const short* __restrict__ Vt,
    const short* __restrict__ w1t, const float* __restrict__ b1,
    const short* __restrict__ w2t, const float* __restrict__ b2,
    float* __restrict__ s_out, float* __restrict__ v_out,
    short* __restrict__ s_out_bf, short* __restrict__ v_out_pk,
    short* __restrict__ abuf, int n) {
    __shared__ short UvL[96][136];
    __shared__ short VvL[96][136];
    __shared__ short catL[32][264];
    __shared__ short hL[32][136];
    const int wave = threadIdx.x >> 6, lane = threadIdx.x & 63;
    const int l15 = lane & 15, l16 = lane >> 4;
    const int rows0 = blockIdx.x * 32;
    const int vr0 = rows0 * 3;
    for (int task = wave; task < 12; task += 8) {
        const int uv = task >= 6;
        const int rem = task - uv * 6;
        const int chunk = rem >> 1, half = rem & 1;
        f32x4 acc[2][4] = {};
        mfma_g<2>(Avv, 3 * n, 128, vr0 + chunk * 32, uv ? Vt : Ut, 128, half * 64, 128, lane, acc);
        short (*dst)[136] = uv ? VvL : UvL;
#pragma unroll
        for (int j = 0; j < 4; j++) {
            int cn = half * 64 + j * 16 + l15;
#pragma unroll
            for (int i = 0; i < 2; i++)
#pragma unroll
                for (int r = 0; r < 4; r++)
                    dst[chunk * 32 + i * 16 + l16 * 4 + r][cn] = f2bf(acc[i][j][r]);
        }
    }
    __syncthreads();
    for (int it = 0; it < 8; it++) {
        int idx = it * 512 + threadIdx.x;
        int r = idx >> 7, g = idx & 127;
        int row = rows0 + r;
        float sv = (row < n) ? s_in[(size_t)row * 128 + g] : 0.f;
        float w0 = bf2f(VvL[3 * r + 0][g]);
        float w1 = bf2f(VvL[3 * r + 1][g]);
        float w2 = bf2f(VvL[3 * r + 2][g]);
        catL[r][g] = f2bf(sv);
        catL[r][128 + g] = f2bf(sqrtf(w0 * w0 + w1 * w1 + w2 * w2));
    }
    __syncthreads();
    if (wave < 4) {
        const int rowblk = wave & 1, colh = wave >> 1;
        f32x4 acc[1][4] = {};
        mfma_l<1>(&catL[0][0], 264, rowblk * 16, w1t, 256, colh * 64, 256, lane, acc);
#pragma unroll
        for (int j = 0; j < 4; j++) {
            int cn = colh * 64 + j * 16 + l15;
            float bb = b1[cn];
#pragma unroll
            for (int r = 0; r < 4; r++) {
                float v = acc[0][j][r] + bb;
                v = v / (1.0f + expf(-v));
                hL[rowblk * 16 + l16 * 4 + r][cn] = f2bf(v);
            }
        }
    }
    __syncthreads();
    for (int task = wave; task < 12; task += 8) {
        const int rowblk = task & 1, colb = task >> 1;
        f32x4 acc[1][4] = {};
        mfma_l<1>(&hL[0][0], 136, rowblk * 16, w2t, 128, colb * 64, 128, lane, acc);
#pragma unroll
        for (int j = 0; j < 4; j++) {
            int gn = colb * 64 + j * 16 + l15;
            float bb = b2[gn];
#pragma unroll
            for (int r = 0; r < 4; r++) {
                int gm = rows0 + rowblk * 16 + l16 * 4 + r;
                if (gm < n) abuf[(size_t)gm * 384 + gn] = f2bf(acc[0][j][r] + bb);
            }
        }
    }
    __threadfence_block();
    __syncthreads();
    for (int it = 0; it < 8; it++) {
        int idx = it * 512 + threadIdx.x;
        int r = idx >> 7, g = idx & 127;
        int row = rows0 + r;
        if (row >= n) continue;
        float u0 = bf2f(UvL[3 * r + 0][g]);
        float u1 = bf2f(UvL[3 * r + 1][g]);
        float u2 = bf2f(UvL[3 * r + 2][g]);
        float w0 = bf2f(VvL[3 * r + 0][g]);
        float w1 = bf2f(VvL[3 * r + 1][g]);
        float w2 = bf2f(VvL[3 * r + 2][g]);
        float inner = u0 * w0 + u1 * w1 + u2 * w2;
        const short* arow = abuf + (size_t)row * 384;
        float ass = bf2f(arow[g]), asv = bf2f(arow[128 + g]), avv = bf2f(arow[256 + g]);
        size_t so = (size_t)row * 128 + g;
        float snew = s_in[so] + ass + asv * inner;
        s_out[so] = snew;
        if (s_out_bf) s_out_bf[so] = f2bf(snew);
        size_t b = (size_t)row * 384;
        float r0 = v_in[b + g] + avv * u0;
        float r1 = v_in[b + 128 + g] + avv * u1;
        float r2 = v_in[b + 256 + g] + avv * u2;
        v_out[b + g] = r0;
        v_out[b + 128 + g] = r1;
        v_out[b + 256 + g] = r2;
        if (v_out_pk) {
            size_t pb = (size_t)row * ROWW + (size_t)g * 6;
            v_out_pk[pb + 3] = f2bf(r0);
            v_out_pk[pb + 4] = f2bf(r1);
            v_out_pk[pb + 5] = f2bf(r2);
        }
    }
}

// ---------------- batched probe gate MLP (z = layer), 64-row, 256 thr ----------------
__global__ __launch_bounds__(256) void k_gate3(
    const short* __restrict__ ms3, const short* __restrict__ g1t, const float* __restrict__ gb1,
    const short* __restrict__ g2t, const float* __restrict__ gb2,
    short* __restrict__ gate3, int P,
    long mszs, long g1zs, long gb1zs, long g2zs, long gb2zs, long gzs) {
    __shared__ short hL[64][264];
    const int z = blockIdx.z;
    const int wave = threadIdx.x >> 6, lane = threadIdx.x & 63;
    const int l15 = lane & 15, l16 = lane >> 4;
    const int rows0 = blockIdx.x * 64;
    const short* ms = ms3 + (size_t)z * mszs;
    {
        f32x4 acc[4][4] = {};
        mfma_g<4>(ms, P, 128, rows0, g1t + (size_t)z * g1zs, 128, wave * 64, 128, lane, acc);
        const float* gb1z = gb1 + (size_t)z * gb1zs;
#pragma unroll
        for (int j = 0; j < 4; j++) {
            int cn = wave * 64 + j * 16 + l15;
            float bb = gb1z[cn];
#pragma unroll
            for (int i = 0; i < 4; i++)
#pragma unroll
                for (int r = 0; r < 4; r++) {
                    float v = acc[i][j][r] + bb;
                    v = v / (1.0f + expf(-v));
                    hL[i * 16 + l16 * 4 + r][cn] = f2bf(v);
                }
        }
    }
    __syncthreads();
    {
        f32x4 acc[4][4] = {};
        mfma_l<4>(&hL[0][0], 264, 0, g2t + (size_t)z * g2zs, 256, wave * 64, 256, lane, acc);
        const float* gb2z = gb2 + (size_t)z * gb2zs;
        short* gz = gate3 + (size_t)z * gzs;
#pragma unroll
        for (int j = 0; j < 4; j++) {
            int gn = wave * 64 + j * 16 + l15;
            float bb = gb2z[gn];
#pragma unroll
            for (int i = 0; i < 4; i++)
#pragma unroll
                for (int r = 0; r < 4; r++) {
                    int gm = rows0 + i * 16 + l16 * 4 + r;
                    if (gm < P)
                        gz[(size_t)gm * 256 + gn] = f2bf(1.0f / (1.0f + expf(-(acc[i][j][r] + bb))));
                }
        }
    }
}

// ---------------- probe layer megakernel (64-row; Uv/Vv via global scratch; 52 KB LDS) ----------------
__global__ __launch_bounds__(512) void k_probe_layer(
    const short* __restrict__ ms, const short* __restrict__ mv,
    const short* __restrict__ gate,
    const short* __restrict__ Ut, const short* __restrict__ Vt,
    const short* __restrict__ w1t, const float* __restrict__ b1,
    const short* __restrict__ w2t, const float* __restrict__ b2,
    float* __restrict__ ps, float* __restrict__ pv,
    short* __restrict__ abuf, short* __restrict__ UvG, short* __restrict__ VvG,
    int P, int first) {
    __shared__ short S2[192 * 136];
    const int tid = threadIdx.x;
    const int wave = tid >> 6, lane = tid & 63;
    const int l15 = lane & 15, l16 = lane >> 4;
    const int rows0 = blockIdx.x * 64;
    // P3: blend (gate from global) -> ps/pv, pvbf -> S2[192][136]
    for (int it = 0; it < 16; it++) {
        int idx = it * 512 + tid;
        int r = idx >> 7, g = idx & 127;
        int row = rows0 + r;
        if (row < P) {
            float gs = bf2f(gate[(size_t)row * 256 + g]);
            float gv = bf2f(gate[(size_t)row * 256 + 128 + g]);
            size_t o = (size_t)row * 128 + g;
            float pso = first ? 0.f : ps[o];
            ps[o] = pso * gs + (1.0f - gs) * bf2f(ms[o]);
#pragma unroll
            for (int i3 = 0; i3 < 3; i3++) {
                size_t o3 = ((size_t)row * 3 + i3) * 128 + g;
                float pvo = first ? 0.f : pv[o3];
                float val = pvo * gv + (1.0f - gv) * bf2f(mv[o3]);
                pv[o3] = val;
                S2[(3 * r + i3) * 136 + g] = f2bf(val);
            }
        } else {
#pragma unroll
            for (int i3 = 0; i3 < 3; i3++) S2[(3 * r + i3) * 136 + g] = 0;
        }
    }
    __syncthreads();
    // P4: Uv = pvbf@Ut -> UvG (global); Vv = pvbf@Vt -> VvG
    if (wave < 6) {
        const int chunk = wave % 3;
        const short* Bt = (wave < 3) ? Ut : Vt;
        short* dst = (wave < 3) ? UvG : VvG;
#pragma unroll
        for (int half = 0; half < 2; half++) {
            f32x4 acc[4][4] = {};
            mfma_l<4>(S2, 136, chunk * 64, Bt, 128, half * 64, 128, lane, acc);
#pragma unroll
            for (int j = 0; j < 4; j++) {
                int cn = half * 64 + j * 16 + l15;
#pragma unroll
                for (int i = 0; i < 4; i++)
#pragma unroll
                    for (int r = 0; r < 4; r++) {
                        int lv = chunk * 64 + i * 16 + l16 * 4 + r;
                        dst[((size_t)(rows0 * 3 + lv)) * 128 + cn] = f2bf(acc[i][j][r]);
                    }
            }
        }
    }
    __threadfence_block();
    __syncthreads();
    // P5: cat -> S2[0..16888) stride 264 (Vv from global)
    for (int it = 0; it < 16; it++) {
        int idx = it * 512 + tid;
        int r = idx >> 7, g = idx & 127;
        int row = rows0 + r;
        float sv = (row < P) ? ps[(size_t)row * 128 + g] : 0.f;
        size_t vb = ((size_t)(rows0 + r) * 3) * 128 + g;
        float w0 = bf2f(VvG[vb + 0 * 128]);
        float w1 = bf2f(VvG[vb + 1 * 128]);
        float w2 = bf2f(VvG[vb + 2 * 128]);
        S2[r * 264 + g] = f2bf(sv);
        S2[r * 264 + 128 + g] = f2bf(sqrtf(w0 * w0 + w1 * w1 + w2 * w2));
    }
    __syncthreads();
    // P6: h = silu(cat@w1t+b1) -> S2 + 16896 (stride 136)
    if (wave < 2) {
        f32x4 acc[4][4] = {};
        mfma_l<4>(S2, 264, 0, w1t, 256, wave * 64, 256, lane, acc);
#pragma unroll
        for (int j = 0; j < 4; j++) {
            int cn = wave * 64 + j * 16 + l15;
            float bb = b1[cn];
#pragma unroll
            for (int i = 0; i < 4; i++)
#pragma unroll
                for (int r = 0; r < 4; r++) {
                    float v = acc[i][j][r] + bb;
                    v = v / (1.0f + expf(-v));
                    S2[16896 + (i * 16 + l16 * 4 + r) * 136 + cn] = f2bf(v);
                }
        }
    }
    __syncthreads();
    // P7: a = h@w2t+b2 -> global abuf
    if (wave < 6) {
        f32x4 acc[4][4] = {};
        mfma_l<4>(S2 + 16896, 136, 0, w2t, 128, wave * 64, 128, lane, acc);
#pragma unroll
        for (int j = 0; j < 4; j++) {
            int gn = wave * 64 + j * 16 + l15;
            float bb = b2[gn];
#pragma unroll
            for (int i = 0; i < 4; i++)
#pragma unroll
                for (int r = 0; r < 4; r++) {
                    int gm = rows0 + i * 16 + l16 * 4 + r;
                    if (gm < P) abuf[(size_t)gm * 384 + gn] = f2bf(acc[i][j][r] + bb);
                }
        }
    }
    __threadfence_block();
    __syncthreads();
    // P8: update (Uv/Vv from global)
    for (int it = 0; it < 16; it++) {
        int idx = it * 512 + tid;
        int r = idx >> 7, g = idx & 127;
        int row = rows0 + r;
        if (row >= P) continue;
        size_t vb = ((size_t)row * 3) * 128 + g;
        float u0 = bf2f(UvG[vb + 0 * 128]);
        float u1 = bf2f(UvG[vb + 1 * 128]);
        float u2 = bf2f(UvG[vb + 2 * 128]);
        float w0 = bf2f(VvG[vb + 0 * 128]);
        float w1 = bf2f(VvG[vb + 1 * 128]);
        float w2 = bf2f(VvG[vb + 2 * 128]);
        float inner = u0 * w0 + u1 * w1 + u2 * w2;
        const short* arow = abuf + (size_t)row * 384;
        float ass = bf2f(arow[g]), asv = bf2f(arow[128 + g]), avv = bf2f(arow[256 + g]);
        size_t so = (size_t)row * 128 + g;
        ps[so] = ps[so] + ass + asv * inner;
        size_t b = (size_t)row * 384;
        pv[b + g] += avv * u0;
        pv[b + 128 + g] += avv * u1;
        pv[b + 256 + g] += avv * u2;
    }
}

// ======== gather ACC on packed 12B rows ========
#define GATHER_ACC(u, Tq, Pq)                                              \
    {                                                                      \
        const float fr = (u).w - (float)((int)(u).w);                      \
        const float a0 = blo((Tq).w0), a1 = bhi((Tq).w0), a2 = blo((Tq).w1); \
        const float f0 = fmaf(fr, bhi((Tq).w1) - a0, a0);                  \
        const float f1 = fmaf(fr, blo((Tq).w2) - a1, a1);                  \
        const float f2 = fmaf(fr, bhi((Tq).w2) - a2, a2);                  \
        const float gsv = f0 * blo((Pq).w0);                               \
        const float gev = f1 * bhi((Pq).w0);                               \
        accs += f2 * blo((Pq).w1);                                         \
        av0 = fmaf(bhi((Pq).w1), gsv, fmaf(gev, (u).x, av0));              \
        av1 = fmaf(blo((Pq).w2), gsv, fmaf(gev, (u).y, av1));              \
        av2 = fmaf(bhi((Pq).w2), gsv, fmaf(gev, (u).z, av2));              \
    }

// ---------------- gather, non-split (256 thr, 2 dests/block, 4-unroll) — probe ----------------
__global__ __launch_bounds__(256) void k_gather_ns(
    const float4* __restrict__ erec, const int* __restrict__ srcs,
    const int* __restrict__ eoff, const short* __restrict__ Tp,
    const short* __restrict__ PV,
    const float* __restrict__ s_in, const float* __restrict__ v_in,
    float* __restrict__ s_out, float* __restrict__ v_out,
    short* __restrict__ s_out_bf, short* __restrict__ v_out_bf, int ndst,
    long tzs, long pvzs, long mszs, long mvzs) {
    const int t = threadIdx.x & 127;
    const int half = threadIdx.x >> 7;
    const int z = blockIdx.z;
    const short* __restrict__ T = Tp + (size_t)z * tzs;
    const short* __restrict__ PVz = PV + (size_t)z * pvzs;
    short* __restrict__ msz = s_out_bf ? s_out_bf + (size_t)z * mszs : nullptr;
    short* __restrict__ mvz = v_out_bf ? v_out_bf + (size_t)z * mvzs : nullptr;

    for (int d = blockIdx.x * 2 + half; d < ndst; d += gridDim.x * 2) {
        const int e0 = eoff[d], e1 = eoff[d + 1];
        float accs = 0.f, av0 = 0.f, av1 = 0.f, av2 = 0.f;

        int ii = e0;
        for (; ii + 3 < e1; ii += 4) {
            const float4 u0 = erec[ii + 0], u1 = erec[ii + 1];
            const float4 u2 = erec[ii + 2], u3 = erec[ii + 3];
            const int s0 = srcs[ii + 0], s1 = srcs[ii + 1];
            const int s2 = srcs[ii + 2], s3 = srcs[ii + 3];
            const U6 T0 = *(const U6*)(T + ((size_t)(int)u0.w * 128 + t) * 6);
            const U6 T1 = *(const U6*)(T + ((size_t)(int)u1.w * 128 + t) * 6);
            const U6 T2 = *(const U6*)(T + ((size_t)(int)u2.w * 128 + t) * 6);
            const U6 T3 = *(const U6*)(T + ((size_t)(int)u3.w * 128 + t) * 6);
            const U6 P0 = *(const U6*)(PVz + ((size_t)s0 * 128 + t) * 6);
            const U6 P1 = *(const U6*)(PVz + ((size_t)s1 * 128 + t) * 6);
            const U6 P2 = *(const U6*)(PVz + ((size_t)s2 * 128 + t) * 6);
            const U6 P3 = *(const U6*)(PVz + ((size_t)s3 * 128 + t) * 6);
            GATHER_ACC(u0, T0, P0); GATHER_ACC(u1, T1, P1);
            GATHER_ACC(u2, T2, P2); GATHER_ACC(u3, T3, P3);
        }
        for (; ii < e1; ++ii) {
            const float4 u = erec[ii];
            const int s = srcs[ii];
            const U6 Tq = *(const U6*)(T + ((size_t)(int)u.w * 128 + t) * 6);
            const U6 Pq = *(const U6*)(PVz + ((size_t)s * 128 + t) * 6);
            GATHER_ACC(u, Tq, Pq);
        }

        if (s_in) {
            accs += s_in[(size_t)d * 128 + t];
            av0 += v_in[(size_t)d * 384 + t];
            av1 += v_in[(size_t)d * 384 + 128 + t];
            av2 += v_in[(size_t)d * 384 + 256 + t];
        }
        if (s_out) {
            s_out[(size_t)d * 128 + t] = accs;
            v_out[(size_t)d * 384 + t] = av0;
            v_out[(size_t)d * 384 + 128 + t] = av1;
            v_out[(size_t)d * 384 + 256 + t] = av2;
        }
        if (msz) msz[(size_t)d * 128 + t] = f2bf(accs);
        if (mvz) {
            mvz[(size_t)(3 * d + 0) * 128 + t] = f2bf(av0);
            mvz[(size_t)(3 * d + 1) * 128 + t] = f2bf(av1);
            mvz[(size_t)(3 * d + 2) * 128 + t] = f2bf(av2);
        }
    }
}

// ---------------- gather, 2-way edge split (512 thr) — atoms ----------------
__global__ __launch_bounds__(512) void k_gather_sp(
    const float4* __restrict__ erec, const int* __restrict__ srcs,
    const int* __restrict__ eoff, const short* __restrict__ Tp,
    const short* __restrict__ PV,
    const float* __restrict__ s_in, const float* __restrict__ v_in,
    float* __restrict__ s_out, float* __restrict__ v_out,
    short* __restrict__ s_out_bf, short* __restrict__ v_out_bf, int ndst,
    long tzs, long pvzs, long mszs, long mvzs) {
    __shared__ float red[2][128][4];
    const int tid = threadIdx.x;
    const int t = tid & 127;
    const int split = (tid >> 7) & 1;
    const int dsel = tid >> 8;
    const int z = blockIdx.z;
    const short* __restrict__ T = Tp + (size_t)z * tzs;
    const short* __restrict__ PVz = PV + (size_t)z * pvzs;
    short* __restrict__ msz = s_out_bf ? s_out_bf + (size_t)z * mszs : nullptr;
    short* __restrict__ mvz = v_out_bf ? v_out_bf + (size_t)z * mvzs : nullptr;

    const int d = blockIdx.x * 2 + dsel;
    const bool valid = d < ndst;
    int e0 = 0, e1 = 0;
    if (valid) { e0 = eoff[d]; e1 = eoff[d + 1]; }
    const int emid = e0 + ((e1 - e0 + 1) >> 1);
    const int lo = split ? emid : e0;
    const int hi = split ? e1 : emid;

    float accs = 0.f, av0 = 0.f, av1 = 0.f, av2 = 0.f;

    int ii = lo;
    for (; ii + 3 < hi; ii += 4) {
        const float4 u0 = erec[ii + 0], u1 = erec[ii + 1];
        const float4 u2 = erec[ii + 2], u3 = erec[ii + 3];
        const int s0 = srcs[ii + 0], s1 = srcs[ii + 1];
        const int s2 = srcs[ii + 2], s3 = srcs[ii + 3];
        const U6 T0 = *(const U6*)(T + ((size_t)(int)u0.w * 128 + t) * 6);
        const U6 T1 = *(const U6*)(T + ((size_t)(int)u1.w * 128 + t) * 6);
        const U6 T2 = *(const U6*)(T + ((size_t)(int)u2.w * 128 + t) * 6);
        const U6 T3 = *(const U6*)(T + ((size_t)(int)u3.w * 128 + t) * 6);
        const U6 P0 = *(const U6*)(PVz + ((size_t)s0 * 128 + t) * 6);
        const U6 P1 = *(const U6*)(PVz + ((size_t)s1 * 128 + t) * 6);
        const U6 P2 = *(const U6*)(PVz + ((size_t)s2 * 128 + t) * 6);
        const U6 P3 = *(const U6*)(PVz + ((size_t)s3 * 128 + t) * 6);
        GATHER_ACC(u0, T0, P0); GATHER_ACC(u1, T1, P1);
        GATHER_ACC(u2, T2, P2); GATHER_ACC(u3, T3, P3);
    }
    for (; ii < hi; ++ii) {
        const float4 u = erec[ii];
        const int s = srcs[ii];
        const U6 Tq = *(const U6*)(T + ((size_t)(int)u.w * 128 + t) * 6);
        const U6 Pq = *(const U6*)(PVz + ((size_t)s * 128 + t) * 6);
        GATHER_ACC(u, Tq, Pq);
    }

    if (split) {
        red[dsel][t][0] = accs; red[dsel][t][1] = av0;
        red[dsel][t][2] = av1;  red[dsel][t][3] = av2;
    }
    __syncthreads();
    if (!split && valid) {
        accs += red[dsel][t][0];
        av0 += red[dsel][t][1];
        av1 += red[dsel][t][2];
        av2 += red[dsel][t][3];
        if (s_in) {
            accs += s_in[(size_t)d * 128 + t];
            av0 += v_in[(size_t)d * 384 + t];
            av1 += v_in[(size_t)d * 384 + 128 + t];
            av2 += v_in[(size_t)d * 384 + 256 + t];
        }
        if (s_out) {
            s_out[(size_t)d * 128 + t] = accs;
            v_out[(size_t)d * 384 + t] = av0;
            v_out[(size_t)d * 384 + 128 + t] = av1;
            v_out[(size_t)d * 384 + 256 + t] = av2;
        }
        if (msz) msz[(size_t)d * 128 + t] = f2bf(accs);
        if (mvz) {
            mvz[(size_t)(3 * d + 0) * 128 + t] = f2bf(av0);
            mvz[(size_t)(3 * d + 1) * 128 + t] = f2bf(av1);
            mvz[(size_t)(3 * d + 2) * 128 + t] = f2bf(av2);
        }
    }
}

extern "C" void kernel_launch(void* const* d_in, const int* in_sizes, int n_in,
                              void* d_out, int out_size, void* d_ws, size_t ws_size,
                              hipStream_t stream) {
    const float* atom_xyz  = (const float*)d_in[0];
    const float* probe_xyz = (const float*)d_in[1];
    const float* cell      = (const float*)d_in[2];
    const float* a_disp    = (const float*)d_in[3];
    const float* p_disp    = (const float*)d_in[4];
    const float* atom_embed= (const float*)d_in[5];
    const float* ai_fw = (const float*)d_in[6];
    const float* ai_fb = (const float*)d_in[7];
    const float* ai_b1 = (const float*)d_in[9];
    const float* ai_b2 = (const float*)d_in[11];
    const float* au_b1 = (const float*)d_in[15];
    const float* au_b2 = (const float*)d_in[17];
    const float* pm_fw = (const float*)d_in[18];
    const float* pm_fb = (const float*)d_in[19];
    const float* pm_b1 = (const float*)d_in[21];
    const float* pm_b2 = (const float*)d_in[23];
    const float* pm_gb1= (const float*)d_in[25];
    const float* pm_gb2= (const float*)d_in[27];
    const float* pu_b1 = (const float*)d_in[31];
    const float* pu_b2 = (const float*)d_in[33];
    const int* nodes_Z = (const int*)d_in[34];
    const int* a_edges = (const int*)d_in[35];
    const int* p_edges = (const int*)d_in[36];

    const int N  = in_sizes[34];
    const int EA = in_sizes[35] / 2;
    const int EP = in_sizes[36] / 2;
    const int P  = in_sizes[1] / 3;

    enum { W_AI_W1=0, W_AI_W2, W_AU_U, W_AU_V, W_AU_W1, W_AU_W2, W_PM_W1, W_PM_W2,
           W_PM_GW1, W_PM_GW2, W_PU_U, W_PU_V, W_PU_W1, W_PU_W2 };
    const int wsrc[14] = {8,10,12,13,14,16,20,22,24,26,28,29,30,32};
    const int wK[14]   = {128,128,128,128,256,128,128,128,128,256,128,128,256,128};
    const int wN[14]   = {128,384,128,128,128,384,128,384,256,256,128,128,128,384};
    size_t woff[15]; woff[0] = 0;
    for (int i = 0; i < 14; i++) woff[i + 1] = woff[i] + (size_t)3 * wK[i] * wN[i];

    char* w = (char*)d_ws;
    size_t off = 0;
    auto alloc = [&](size_t bytes) -> void* {
        void* p = w + off;
        off = (off + bytes + 255) & ~(size_t)255;
        return p;
    };
    int* a_off  = (int*)alloc((size_t)(N + 1) * 4);
    int* a_cur  = (int*)alloc((size_t)N * 4);
    int* a_eids = (int*)alloc((size_t)EA * 4);
    int* a_srcs = (int*)alloc((size_t)EA * 4);
    int* p_off  = (int*)alloc((size_t)(P + 1) * 4);
    int* p_cur  = (int*)alloc((size_t)P * 4);
    int* p_eids = (int*)alloc((size_t)EP * 4);
    int* p_srcs = (int*)alloc((size_t)EP * 4);
    float4* a_erec = (float4*)alloc((size_t)EA * 16);
    float4* p_erec = (float4*)alloc((size_t)EP * 16);
    float* Sp   = (float*)alloc((size_t)(BINS + 1) * 32 * 4);
    float* fwp  = (float*)alloc((size_t)6 * 32 * 384 * 4);
    short* Tbf  = (short*)alloc((size_t)6 * (BINS + 1) * 512 * 2);
    short* Tp   = (short*)alloc((size_t)6 * BINS * ROWW * 2);
    short* wbt  = (short*)alloc(woff[14] * 2);
    float* s0     = (float*)alloc((size_t)N * F * 4);
    float* v0     = (float*)alloc((size_t)N * 3 * F * 4);
    float* s_list = (float*)alloc((size_t)LAYERS * N * F * 4);
    float* v_list = (float*)alloc((size_t)LAYERS * N * 3 * F * 4);
    float* msf    = (float*)alloc((size_t)N * F * 4);
    float* mvf    = (float*)alloc((size_t)N * 3 * F * 4);
    short* s0_bf    = (short*)alloc((size_t)N * F * 2);
    short* sbf_list = (short*)alloc((size_t)LAYERS * N * F * 2);
    short* vpk6     = (short*)alloc((size_t)4 * N * ROWW * 2);
    short* ms3      = (short*)alloc((size_t)3 * P * F * 2);
    short* mv3      = (short*)alloc((size_t)3 * 3 * P * F * 2);
    short* gate3    = (short*)alloc((size_t)3 * P * 256 * 2);
    short* mv_bf    = (short*)alloc((size_t)N * 3 * F * 2);
    short* abuf_bf  = (short*)alloc((size_t)P * 3 * F * 2);
    short* UvG      = (short*)alloc((size_t)3 * P * F * 2);
    short* VvG      = (short*)alloc((size_t)3 * P * F * 2);
    (void)ws_size; (void)n_in;

    // CSR atoms (cutoff-filtered)
    hipMemsetAsync(a_cur, 0, (size_t)N * 4, stream);
    k_count<<<(EA + 255) / 256, 256, 0, stream>>>(a_edges, atom_xyz, atom_xyz, a_disp, cell, a_cur, EA);
    k_scan<<<1, 1024, 0, stream>>>(a_cur, a_off, N);
    hipMemcpyAsync(a_cur, a_off, (size_t)N * 4, hipMemcpyDeviceToDevice, stream);
    k_scatter<<<(EA + 255) / 256, 256, 0, stream>>>(a_edges, atom_xyz, atom_xyz, a_disp, cell, a_cur, a_eids, EA);
    // CSR probes
    hipMemsetAsync(p_cur, 0, (size_t)P * 4, stream);
    k_count<<<(EP + 255) / 256, 256, 0, stream>>>(p_edges, atom_xyz, probe_xyz, p_disp, cell, p_cur, EP);
    k_scan<<<1, 1024, 0, stream>>>(p_cur, p_off, P);
    hipMemcpyAsync(p_cur, p_off, (size_t)P * 4, hipMemcpyDeviceToDevice, stream);
    k_scatter<<<(EP + 255) / 256, 256, 0, stream>>>(p_edges, atom_xyz, probe_xyz, p_disp, cell, p_cur, p_eids, EP);

    // edge records
    k_geom_rec<<<(EA + 255) / 256, 256, 0, stream>>>(atom_xyz, atom_xyz, a_disp, cell, a_edges,
                                                     a_eids, a_off, N, a_erec, a_srcs);
    k_geom_rec<<<(EP + 255) / 256, 256, 0, stream>>>(atom_xyz, probe_xyz, p_disp, cell, p_edges,
                                                     p_eids, p_off, P, p_erec, p_srcs);

    // filter tables
    k_sbuild<<<(BINS + 256) / 256, 256, 0, stream>>>(Sp);
    k_fwpack<<<(6 * 32 * 384 + 255) / 256, 256, 0, stream>>>(ai_fw, ai_fb, pm_fw, pm_fb, fwp);
    {
        dim3 g(384 / 64, (BINS + 1 + 63) / 64, 6);
        k_gemm<<<g, 256, 0, stream>>>(Sp, fwp, Tbf, BINS + 1, 384, 32, 4, 32 * 384, (BINS + 1) * 512);
    }
    k_tpack<<<(6 * BINS * 128 + 255) / 256, 256, 0, stream>>>(Tbf, Tp);

    // weights -> bf16 transposed
    {
        CvtArgs ca;
        for (int i = 0; i < 14; i++) {
            ca.src[i] = (const float*)d_in[wsrc[i]];
            ca.dstoff[i] = (int)woff[i];
            ca.Kk[i] = wK[i]; ca.Nn[i] = wN[i];
        }
        k_cvtw<<<dim3(64, 14, 3), 256, 0, stream>>>(ca, wbt);
    }
    auto wt = [&](int a, int l) { return wbt + woff[a] + (size_t)l * wK[a] * wN[a]; };

    // init node states
    k_embed<<<(N * F + 255) / 256, 256, 0, stream>>>(nodes_Z, atom_embed, s0, s0_bf, N);
    hipMemsetAsync(v0, 0, (size_t)N * 3 * F * 4, stream);
    hipMemsetAsync(vpk6, 0, (size_t)N * ROWW * 2, stream);

    auto pvbuf = [&](int idx) { return vpk6 + (size_t)idx * N * ROWW; };
    const int nb_atom32 = (N + 31) / 32;
    const int nb_probe64 = (P + 63) / 64;

    // ---- atom message-passing layers ----
    for (int l = 0; l < LAYERS; l++) {
        const float* scur = l ? (s_list + (size_t)(l - 1) * N * F) : s0;
        const float* vcur = l ? (v_list + (size_t)(l - 1) * N * 3 * F) : v0;
        const short* scur_bf = l ? (sbf_list + (size_t)(l - 1) * N * F) : s0_bf;
        k_mlp2<<<dim3(nb_atom32, 1, 1), 512, 0, stream>>>(
            scur_bf, wt(W_AI_W1, l), ai_b1 + (size_t)l * F,
            wt(W_AI_W2, l), ai_b2 + (size_t)l * 3 * F,
            pvbuf(l), N, 0, 0, 0, 0, 0, 0);
        k_gather_sp<<<dim3((N + 1) / 2, 1, 1), 512, 0, stream>>>(a_erec, a_srcs, a_off,
                 Tp + (size_t)l * BINS * ROWW, pvbuf(l),
                 scur, vcur, msf, mvf, nullptr, mv_bf, N, 0, 0, 0, 0);
        k_paiupd<<<dim3(nb_atom32), 512, 0, stream>>>(
            mv_bf, msf, mvf,
            wt(W_AU_U, l), wt(W_AU_V, l),
            wt(W_AU_W1, l), au_b1 + (size_t)l * F,
            wt(W_AU_W2, l), au_b2 + (size_t)l * 3 * F,
            s_list + (size_t)l * N * F, v_list + (size_t)l * N * 3 * F,
            sbf_list + (size_t)l * N * F, pvbuf(l + 1), abuf_bf, N);
    }

    // ---- probe phase ----
    float* ps = (float*)d_out;
    float* pv = (float*)d_out + (size_t)P * F;

    // batched probe phi (all 3 layers) -> pvbuf(1..3) slots 0-2
    k_mlp2<<<dim3(nb_atom32, 1, 3), 512, 0, stream>>>(
        sbf_list, wt(W_PM_W1, 0), pm_b1, wt(W_PM_W2, 0), pm_b2,
        pvbuf(1), N,
        (long)N * F, (long)128 * 128, 128, (long)128 * 384, 384, (long)N * ROWW);

    // fused 3-layer probe gather
    k_gather_ns<<<dim3((P + 1) / 2, 1, 3), 256, 0, stream>>>(p_erec, p_srcs, p_off,
             Tp + (size_t)3 * BINS * ROWW, pvbuf(1),
             nullptr, nullptr, nullptr, nullptr, ms3, mv3, P,
             (long)BINS * ROWW, (long)N * ROWW, (long)P * F, (long)3 * P * F);

    // batched probe gates (all 3 layers): depend only on ms3
    k_gate3<<<dim3(nb_probe64, 1, 3), 256, 0, stream>>>(
        ms3, wt(W_PM_GW1, 0), pm_gb1, wt(W_PM_GW2, 0), pm_gb2, gate3, P,
        (long)P * F, (long)128 * 256, 256, (long)256 * 256, 256, (long)P * 256);

    for (int l = 0; l < LAYERS; l++) {
        k_probe_layer<<<dim3(nb_probe64), 512, 0, stream>>>(
            ms3 + (size_t)l * P * F, mv3 + (size_t)l * 3 * P * F,
            gate3 + (size_t)l * P * 256,
            wt(W_PU_U, l), wt(W_PU_V, l),
            wt(W_PU_W1, l), pu_b1 + (size_t)l * F,
            wt(W_PU_W2, l), pu_b2 + (size_t)l * 3 * F,
            ps, pv, abuf_bf, UvG, VvG, P, l == 0);
    }
}

// Round 17
// 610.513 us; speedup vs baseline: 1.0286x; 1.0286x over previous
//
#include <hip/hip_runtime.h>
#include <hip/hip_bf16.h>
#include <math.h>

#define PI_F 3.14159265358979323846f

static constexpr int F = 128;
static constexpr int KB = 30;
static constexpr int LAYERS = 3;
static constexpr float CUT = 4.0f;
static constexpr int BINS = 512;
static constexpr int ROWW = 768;   // packed row stride in shorts: 128 lanes * 6

typedef short bf16x8 __attribute__((ext_vector_type(8)));
typedef float f32x4 __attribute__((ext_vector_type(4)));

struct __attribute__((packed, aligned(4))) U6 { unsigned int w0, w1, w2; };

__device__ __forceinline__ float bf2f(unsigned short u) {
    union { unsigned int i; float f; } c; c.i = ((unsigned int)u) << 16; return c.f;
}
__device__ __forceinline__ float blo(unsigned int w) {
    union { unsigned int i; float f; } c; c.i = w << 16; return c.f;
}
__device__ __forceinline__ float bhi(unsigned int w) {
    union { unsigned int i; float f; } c; c.i = w & 0xffff0000u; return c.f;
}
__device__ __forceinline__ short f2bf(float x) {
    union { float f; unsigned int u; } c; c.f = x;
    unsigned int r = c.u + 0x7FFFu + ((c.u >> 16) & 1u);
    return (short)(r >> 16);
}

__device__ __forceinline__ float edge_dist(const float* __restrict__ sxyz,
                                           const float* __restrict__ dxyz,
                                           const float* __restrict__ disp,
                                           const float* __restrict__ cell,
                                           int s, int d, int e, float* dx) {
    const float* dp = disp + 3 * (size_t)e;
#pragma unroll
    for (int i = 0; i < 3; i++) {
        float dc = dp[0] * cell[0 * 3 + i] + dp[1] * cell[1 * 3 + i] + dp[2] * cell[2 * 3 + i];
        dx[i] = dxyz[3 * d + i] - (sxyz[3 * s + i] + dc);
    }
    return sqrtf(dx[0] * dx[0] + dx[1] * dx[1] + dx[2] * dx[2]);
}

// ---------------- CSR build (cutoff-filtered) ----------------
__global__ void k_count(const int* __restrict__ edges, const float* __restrict__ sxyz,
                        const float* __restrict__ dxyz, const float* __restrict__ disp,
                        const float* __restrict__ cell, int* __restrict__ cnt, int E) {
    int i = blockIdx.x * blockDim.x + threadIdx.x;
    if (i >= E) return;
    int s = edges[2 * i], d = edges[2 * i + 1];
    float dx[3];
    float dist = edge_dist(sxyz, dxyz, disp, cell, s, d, i, dx);
    if (dist < CUT) atomicAdd(&cnt[d], 1);
}

__global__ void k_scan(const int* __restrict__ cnt, int* __restrict__ off, int n) {
    __shared__ int part[1024];
    int t = threadIdx.x;
    int chunk = (n + 1023) / 1024;
    int b = t * chunk; if (b > n) b = n;
    int e = b + chunk; if (e > n) e = n;
    int s = 0;
    for (int i = b; i < e; i++) s += cnt[i];
    part[t] = s;
    __syncthreads();
    for (int o = 1; o < 1024; o <<= 1) {
        int v = part[t];
        int add = (t >= o) ? part[t - o] : 0;
        __syncthreads();
        part[t] = v + add;
        __syncthreads();
    }
    int run = (t == 0) ? 0 : part[t - 1];
    for (int i = b; i < e; i++) { off[i] = run; run += cnt[i]; }
    if (t == 1023) off[n] = part[1023];
}

__global__ void k_scatter(const int* __restrict__ edges, const float* __restrict__ sxyz,
                          const float* __restrict__ dxyz, const float* __restrict__ disp,
                          const float* __restrict__ cell, int* __restrict__ cur,
                          int* __restrict__ eids, int E) {
    int i = blockIdx.x * blockDim.x + threadIdx.x;
    if (i >= E) return;
    int s = edges[2 * i], d = edges[2 * i + 1];
    float dx[3];
    float dist = edge_dist(sxyz, dxyz, disp, cell, s, d, i, dx);
    if (dist < CUT) {
        int pos = atomicAdd(&cur[d], 1);
        eids[pos] = i;
    }
}

// ---------------- edge records, CSR-ordered ----------------
__global__ void k_geom_rec(const float* __restrict__ sxyz, const float* __restrict__ dxyz,
                           const float* __restrict__ disp, const float* __restrict__ cell,
                           const int* __restrict__ edges, const int* __restrict__ eids,
                           const int* __restrict__ eoff, int ndst,
                           float4* __restrict__ erec, int* __restrict__ srcs) {
    int pos = blockIdx.x * blockDim.x + threadIdx.x;
    if (pos >= eoff[ndst]) return;
    int e = eids[pos];
    int s = edges[2 * e], d = edges[2 * e + 1];
    float dx[3];
    float dist = edge_dist(sxyz, dxyz, disp, cell, s, d, e, dx);
    float inv = 1.0f / fmaxf(dist, 1e-12f);
    float db = fminf(dist * ((float)BINS / CUT), (float)BINS - 0.0001f);
    erec[pos] = make_float4(dx[0] * inv, dx[1] * inv, dx[2] * inv, db);
    srcs[pos] = s;
}

// ---------------- S' basis ----------------
__global__ void k_sbuild(float* __restrict__ Sp) {
    int i = blockIdx.x * blockDim.x + threadIdx.x;
    if (i > BINS) return;
    float d = (float)i * (CUT / (float)BINS);
    float cc = (d < CUT) ? 0.5f * (cosf(PI_F * d / CUT) + 1.0f) : 0.0f;
    float* row = Sp + (size_t)i * 32;
#pragma unroll
    for (int k = 0; k < KB; k++) {
        float kk = (float)(k + 1);
        float st = (d > 1e-12f) ? sinf(PI_F * d * kk / CUT) / d : PI_F * kk / CUT;
        row[k] = cc * st;
    }
    row[30] = cc;
    row[31] = 0.f;
}

// ---------------- assemble fw' ----------------
__global__ void k_fwpack(const float* __restrict__ ai_fw, const float* __restrict__ ai_fb,
                         const float* __restrict__ pm_fw, const float* __restrict__ pm_fb,
                         float* __restrict__ fwp) {
    int i = blockIdx.x * blockDim.x + threadIdx.x;
    if (i >= 6 * 32 * 384) return;
    int tbl = i / (32 * 384);
    int k = (i / 384) % 32;
    int c = i % 384;
    const float* fw = (tbl < 3) ? ai_fw + (size_t)tbl * KB * 384 : pm_fw + (size_t)(tbl - 3) * KB * 384;
    const float* fb = (tbl < 3) ? ai_fb + (size_t)tbl * 384 : pm_fb + (size_t)(tbl - 3) * 384;
    float v = 0.f;
    if (k < KB) v = fw[(size_t)k * 384 + c];
    else if (k == 30) v = fb[c];
    fwp[i] = v;
}

// ---------------- interleave table pairs -> packed 6-short rows ----------------
__global__ void k_tpack(const short* __restrict__ Tbf, short* __restrict__ Tp) {
    int i = blockIdx.x * blockDim.x + threadIdx.x;
    if (i >= 6 * BINS * 128) return;
    int tbl = i / (BINS * 128);
    int rem = i % (BINS * 128);
    int bin = rem >> 7, lane = rem & 127;
    const short* a = Tbf + ((size_t)tbl * (BINS + 1) + bin) * 512 + lane * 4;
    const short* b = a + 512;
    short* o = Tp + ((size_t)tbl * BINS + bin) * ROWW + lane * 6;
    o[0] = a[0]; o[1] = a[1]; o[2] = a[2];
    o[3] = b[0]; o[4] = b[1]; o[5] = b[2];
}

// ---------------- weight transpose+cvt ----------------
struct CvtArgs {
    const float* src[14];
    int dstoff[14];
    int Kk[14];
    int Nn[14];
};
__global__ __launch_bounds__(256) void k_cvtw(CvtArgs a, short* __restrict__ dst) {
    int arr = blockIdx.y, l = blockIdx.z;
    int K = a.Kk[arr], N = a.Nn[arr];
    int tilesx = N / 32, tilesy = K / 32;
    int tile = blockIdx.x;
    if (tile >= tilesx * tilesy) return;
    int tn = (tile % tilesx) * 32, tk = (tile / tilesx) * 32;
    __shared__ float tb[32][33];
    int tx = threadIdx.x & 31, ty = threadIdx.x >> 5;
    const float* src = a.src[arr] + (size_t)l * K * N;
    short* d = dst + a.dstoff[arr] + (size_t)l * K * N;
#pragma unroll
    for (int r = 0; r < 4; r++)
        tb[ty * 4 + r][tx] = src[(size_t)(tk + ty * 4 + r) * N + tn + tx];
    __syncthreads();
#pragma unroll
    for (int r = 0; r < 4; r++)
        d[(size_t)(tn + ty * 4 + r) * K + tk + tx] = f2bf(tb[tx][ty * 4 + r]);
}

// ---------------- init ----------------
__global__ void k_embed(const int* __restrict__ Z, const float* __restrict__ emb,
                        float* __restrict__ s, short* __restrict__ sbf, int n) {
    int i = blockIdx.x * blockDim.x + threadIdx.x;
    if (i < n * F) {
        float v = emb[(size_t)Z[i / F] * F + (i % F)];
        s[i] = v; sbf[i] = f2bf(v);
    }
}

// ---------------- f32 VALU GEMM (table build only) ----------------
__global__ __launch_bounds__(256) void k_gemm(const float* __restrict__ A, const float* __restrict__ B,
                                              void* __restrict__ Cout,
                                              int M, int N, int K, int outmode,
                                              int bstride, int cstride) {
    __shared__ float As[16][64];
    __shared__ float Bs[16][64];
    const float* Bz = B + (size_t)blockIdx.z * bstride;
    int tid = threadIdx.x;
    int bm = blockIdx.y * 64, bn = blockIdx.x * 64;
    int tx = tid & 15, ty = tid >> 4;
    float acc[4][4] = {};
    int arow = tid >> 2;
    int acol = (tid & 3) * 4;
    int brow = tid >> 4;
    int bcol = (tid & 15) * 4;
    for (int k0 = 0; k0 < K; k0 += 16) {
        float4 av = make_float4(0.f, 0.f, 0.f, 0.f);
        int gm = bm + arow;
        if (gm < M) av = *reinterpret_cast<const float4*>(A + (size_t)gm * K + k0 + acol);
        As[acol + 0][arow] = av.x; As[acol + 1][arow] = av.y;
        As[acol + 2][arow] = av.z; As[acol + 3][arow] = av.w;
        float4 bv = *reinterpret_cast<const float4*>(Bz + (size_t)(k0 + brow) * N + bn + bcol);
        Bs[brow][bcol + 0] = bv.x; Bs[brow][bcol + 1] = bv.y;
        Bs[brow][bcol + 2] = bv.z; Bs[brow][bcol + 3] = bv.w;
        __syncthreads();
#pragma unroll
        for (int k = 0; k < 16; k++) {
            float a0 = As[k][ty * 4 + 0], a1 = As[k][ty * 4 + 1];
            float a2 = As[k][ty * 4 + 2], a3 = As[k][ty * 4 + 3];
            float b0 = Bs[k][tx * 4 + 0], b1 = Bs[k][tx * 4 + 1];
            float b2 = Bs[k][tx * 4 + 2], b3 = Bs[k][tx * 4 + 3];
            acc[0][0] += a0 * b0; acc[0][1] += a0 * b1; acc[0][2] += a0 * b2; acc[0][3] += a0 * b3;
            acc[1][0] += a1 * b0; acc[1][1] += a1 * b1; acc[1][2] += a1 * b2; acc[1][3] += a1 * b3;
            acc[2][0] += a2 * b0; acc[2][1] += a2 * b1; acc[2][2] += a2 * b2; acc[2][3] += a2 * b3;
            acc[3][0] += a3 * b0; acc[3][1] += a3 * b1; acc[3][2] += a3 * b2; acc[3][3] += a3 * b3;
        }
        __syncthreads();
    }
#pragma unroll
    for (int i = 0; i < 4; i++) {
        int gm = bm + ty * 4 + i;
        if (gm >= M) continue;
#pragma unroll
        for (int j = 0; j < 4; j++) {
            int gn = bn + tx * 4 + j;
            float v = acc[i][j];
            if (outmode == 0) ((float*)Cout)[(size_t)gm * N + gn] = v;
            else ((short*)Cout)[(size_t)blockIdx.z * cstride + (size_t)gm * 512 + (gn & 127) * 4 + (gn >> 7)] = f2bf(v);
        }
    }
}

// ======== templated MFMA wave-tile helpers ========
template<int RF>
__device__ __forceinline__ void mfma_g(
    const short* __restrict__ A, int arows, int Astride, int row0,
    const short* __restrict__ Bt, int Bstride, int col0, int K,
    int lane, f32x4 acc[RF][4]) {
    const int l15 = lane & 15, l16 = lane >> 4;
    for (int k0 = 0; k0 < K; k0 += 32) {
        const int kbase = k0 + l16 * 8;
        bf16x8 af[RF], bfr[4];
#pragma unroll
        for (int i = 0; i < RF; i++) {
            int r = row0 + i * 16 + l15;
            bf16x8 t = {};
            if (r < arows) t = *reinterpret_cast<const bf16x8*>(A + (size_t)r * Astride + kbase);
            af[i] = t;
        }
#pragma unroll
        for (int j = 0; j < 4; j++)
            bfr[j] = *reinterpret_cast<const bf16x8*>(Bt + (size_t)(col0 + j * 16 + l15) * Bstride + kbase);
#pragma unroll
        for (int i = 0; i < RF; i++)
#pragma unroll
            for (int j = 0; j < 4; j++)
                acc[i][j] = __builtin_amdgcn_mfma_f32_16x16x32_bf16(af[i], bfr[j], acc[i][j], 0, 0, 0);
    }
}
template<int RF>
__device__ __forceinline__ void mfma_l(
    const short* __restrict__ Alds, int Astride, int lrow0,
    const short* __restrict__ Bt, int Bstride, int col0, int K,
    int lane, f32x4 acc[RF][4]) {
    const int l15 = lane & 15, l16 = lane >> 4;
    for (int k0 = 0; k0 < K; k0 += 32) {
        const int kbase = k0 + l16 * 8;
        bf16x8 af[RF], bfr[4];
#pragma unroll
        for (int i = 0; i < RF; i++)
            af[i] = *reinterpret_cast<const bf16x8*>(Alds + (size_t)(lrow0 + i * 16 + l15) * Astride + kbase);
#pragma unroll
        for (int j = 0; j < 4; j++)
            bfr[j] = *reinterpret_cast<const bf16x8*>(Bt + (size_t)(col0 + j * 16 + l15) * Bstride + kbase);
#pragma unroll
        for (int i = 0; i < RF; i++)
#pragma unroll
            for (int j = 0; j < 4; j++)
                acc[i][j] = __builtin_amdgcn_mfma_f32_16x16x32_bf16(af[i], bfr[j], acc[i][j], 0, 0, 0);
    }
}

// ---------------- fused MLP2, 32-row tiles (atom-side) ----------------
__global__ __launch_bounds__(512) void k_mlp2(
    const short* __restrict__ X, const short* __restrict__ w1t, const float* __restrict__ b1,
    const short* __restrict__ w2t, const float* __restrict__ b2,
    short* __restrict__ PV, int M,
    long xzs, long w1zs, long b1zs, long w2zs, long b2zs, long pvzs) {
    __shared__ short hL[32][136];
    const int z = blockIdx.z;
    const int wave = threadIdx.x >> 6, lane = threadIdx.x & 63;
    const int l15 = lane & 15, l16 = lane >> 4;
    const int rows0 = blockIdx.x * 32;
    const short* Xz = X + (size_t)z * xzs;
    if (wave < 4) {
        const int rowblk = wave & 1, colh = wave >> 1;
        f32x4 acc[1][4] = {};
        mfma_g<1>(Xz, M, 128, rows0 + rowblk * 16, w1t + (size_t)z * w1zs, 128, colh * 64, 128, lane, acc);
        const float* b1z = b1 + (size_t)z * b1zs;
#pragma unroll
        for (int j = 0; j < 4; j++) {
            int cn = colh * 64 + j * 16 + l15;
            float bb = b1z[cn];
#pragma unroll
            for (int r = 0; r < 4; r++) {
                float v = acc[0][j][r] + bb;
                v = v / (1.0f + expf(-v));
                hL[rowblk * 16 + l16 * 4 + r][cn] = f2bf(v);
            }
        }
    }
    __syncthreads();
    short* PVz = PV + (size_t)z * pvzs;
    const float* b2z = b2 + (size_t)z * b2zs;
    for (int task = wave; task < 12; task += 8) {
        const int rowblk = task & 1, colb = task >> 1;
        f32x4 acc[1][4] = {};
        mfma_l<1>(&hL[0][0], 136, rowblk * 16, w2t + (size_t)z * w2zs, 128, colb * 64, 128, lane, acc);
#pragma unroll
        for (int j = 0; j < 4; j++) {
            int gn = colb * 64 + j * 16 + l15;
            float bb = b2z[gn];
#pragma unroll
            for (int r = 0; r < 4; r++) {
                int gm = rows0 + rowblk * 16 + l16 * 4 + r;
                if (gm < M)
                    PVz[(size_t)gm * ROWW + (gn & 127) * 6 + (gn >> 7)] = f2bf(acc[0][j][r] + bb);
            }
        }
    }
}

// ---------------- fused atom PaiNN update, 32-row tiles ----------------
__global__ __launch_bounds__(512) void k_paiupd(
    const short* __restrict__ Avv,
    const float* __restrict__ s_in,
    const float* __restrict__ v_in,
    const short* __restrict__ Ut, const short* __restrict__ Vt,
    const short* __restrict__ w1t, const float* __restrict__ b1,
    const short* __restrict__ w2t, const float* __restrict__ b2,
    float* __restrict__ s_out, float* __restrict__ v_out,
    short* __restrict__ s_out_bf, short* __restrict__ v_out_pk,
    short* __restrict__ abuf, int n) {
    __shared__ short UvL[96][136];
    __shared__ short VvL[96][136];
    __shared__ short catL[32][264];
    __shared__ short hL[32][136];
    const int wave = threadIdx.x >> 6, lane = threadIdx.x & 63;
    const int l15 = lane & 15, l16 = lane >> 4;
    const int rows0 = blockIdx.x * 32;
    const int vr0 = rows0 * 3;
    for (int task = wave; task < 12; task += 8) {
        const int uv = task >= 6;
        const int rem = task - uv * 6;
        const int chunk = rem >> 1, half = rem & 1;
        f32x4 acc[2][4] = {};
        mfma_g<2>(Avv, 3 * n, 128, vr0 + chunk * 32, uv ? Vt : Ut, 128, half * 64, 128, lane, acc);
        short (*dst)[136] = uv ? VvL : UvL;
#pragma unroll
        for (int j = 0; j < 4; j++) {
            int cn = half * 64 + j * 16 + l15;
#pragma unroll
            for (int i = 0; i < 2; i++)
#pragma unroll
                for (int r = 0; r < 4; r++)
                    dst[chunk * 32 + i * 16 + l16 * 4 + r][cn] = f2bf(acc[i][j][r]);
        }
    }
    __syncthreads();
    for (int it = 0; it < 8; it++) {
        int idx = it * 512 + threadIdx.x;
        int r = idx >> 7, g = idx & 127;
        int row = rows0 + r;
        float sv = (row < n) ? s_in[(size_t)row * 128 + g] : 0.f;
        float w0 = bf2f(VvL[3 * r + 0][g]);
        float w1 = bf2f(VvL[3 * r + 1][g]);
        float w2 = bf2f(VvL[3 * r + 2][g]);
        catL[r][g] = f2bf(sv);
        catL[r][128 + g] = f2bf(sqrtf(w0 * w0 + w1 * w1 + w2 * w2));
    }
    __syncthreads();
    if (wave < 4) {
        const int rowblk = wave & 1, colh = wave >> 1;
        f32x4 acc[1][4] = {};
        mfma_l<1>(&catL[0][0], 264, rowblk * 16, w1t, 256, colh * 64, 256, lane, acc);
#pragma unroll
        for (int j = 0; j < 4; j++) {
            int cn = colh * 64 + j * 16 + l15;
            float bb = b1[cn];
#pragma unroll
            for (int r = 0; r < 4; r++) {
                float v = acc[0][j][r] + bb;
                v = v / (1.0f + expf(-v));
                hL[rowblk * 16 + l16 * 4 + r][cn] = f2bf(v);
            }
        }
    }
    __syncthreads();
    for (int task = wave; task < 12; task += 8) {
        const int rowblk = task & 1, colb = task >> 1;
        f32x4 acc[1][4] = {};
        mfma_l<1>(&hL[0][0], 136, rowblk * 16, w2t, 128, colb * 64, 128, lane, acc);
#pragma unroll
        for (int j = 0; j < 4; j++) {
            int gn = colb * 64 + j * 16 + l15;
            float bb = b2[gn];
#pragma unroll
            for (int r = 0; r < 4; r++) {
                int gm = rows0 + rowblk * 16 + l16 * 4 + r;
                if (gm < n) abuf[(size_t)gm * 384 + gn] = f2bf(acc[0][j][r] + bb);
            }
        }
    }
    __threadfence_block();
    __syncthreads();
    for (int it = 0; it < 8; it++) {
        int idx = it * 512 + threadIdx.x;
        int r = idx >> 7, g = idx & 127;
        int row = rows0 + r;
        if (row >= n) continue;
        float u0 = bf2f(UvL[3 * r + 0][g]);
        float u1 = bf2f(UvL[3 * r + 1][g]);
        float u2 = bf2f(UvL[3 * r + 2][g]);
        float w0 = bf2f(VvL[3 * r + 0][g]);
        float w1 = bf2f(VvL[3 * r + 1][g]);
        float w2 = bf2f(VvL[3 * r + 2][g]);
        float inner = u0 * w0 + u1 * w1 + u2 * w2;
        const short* arow = abuf + (size_t)row * 384;
        float ass = bf2f(arow[g]), asv = bf2f(arow[128 + g]), avv = bf2f(arow[256 + g]);
        size_t so = (size_t)row * 128 + g;
        float snew = s_in[so] + ass + asv * inner;
        s_out[so] = snew;
        if (s_out_bf) s_out_bf[so] = f2bf(snew);
        size_t b = (size_t)row * 384;
        float r0 = v_in[b + g] + avv * u0;
        float r1 = v_in[b + 128 + g] + avv * u1;
        float r2 = v_in[b + 256 + g] + avv * u2;
        v_out[b + g] = r0;
        v_out[b + 128 + g] = r1;
        v_out[b + 256 + g] = r2;
        if (v_out_pk) {
            size_t pb = (size_t)row * ROWW + (size_t)g * 6;
            v_out_pk[pb + 3] = f2bf(r0);
            v_out_pk[pb + 4] = f2bf(r1);
            v_out_pk[pb + 5] = f2bf(r2);
        }
    }
}

// ---------------- batched probe gate MLP (z = layer), 64-row, 256 thr ----------------
__global__ __launch_bounds__(256) void k_gate3(
    const short* __restrict__ ms3, const short* __restrict__ g1t, const float* __restrict__ gb1,
    const short* __restrict__ g2t, const float* __restrict__ gb2,
    short* __restrict__ gate3, int P,
    long mszs, long g1zs, long gb1zs, long g2zs, long gb2zs, long gzs) {
    __shared__ short hL[64][264];
    const int z = blockIdx.z;
    const int wave = threadIdx.x >> 6, lane = threadIdx.x & 63;
    const int l15 = lane & 15, l16 = lane >> 4;
    const int rows0 = blockIdx.x * 64;
    const short* ms = ms3 + (size_t)z * mszs;
    {
        f32x4 acc[4][4] = {};
        mfma_g<4>(ms, P, 128, rows0, g1t + (size_t)z * g1zs, 128, wave * 64, 128, lane, acc);
        const float* gb1z = gb1 + (size_t)z * gb1zs;
#pragma unroll
        for (int j = 0; j < 4; j++) {
            int cn = wave * 64 + j * 16 + l15;
            float bb = gb1z[cn];
#pragma unroll
            for (int i = 0; i < 4; i++)
#pragma unroll
                for (int r = 0; r < 4; r++) {
                    float v = acc[i][j][r] + bb;
                    v = v / (1.0f + expf(-v));
                    hL[i * 16 + l16 * 4 + r][cn] = f2bf(v);
                }
        }
    }
    __syncthreads();
    {
        f32x4 acc[4][4] = {};
        mfma_l<4>(&hL[0][0], 264, 0, g2t + (size_t)z * g2zs, 256, wave * 64, 256, lane, acc);
        const float* gb2z = gb2 + (size_t)z * gb2zs;
        short* gz = gate3 + (size_t)z * gzs;
#pragma unroll
        for (int j = 0; j < 4; j++) {
            int gn = wave * 64 + j * 16 + l15;
            float bb = gb2z[gn];
#pragma unroll
            for (int i = 0; i < 4; i++)
#pragma unroll
                for (int r = 0; r < 4; r++) {
                    int gm = rows0 + i * 16 + l16 * 4 + r;
                    if (gm < P)
                        gz[(size_t)gm * 256 + gn] = f2bf(1.0f / (1.0f + expf(-(acc[i][j][r] + bb))));
                }
        }
    }
}

// ---------------- probe layer megakernel (64-row, gate precomputed) ----------------
__global__ __launch_bounds__(512) void k_probe_layer(
    const short* __restrict__ ms, const short* __restrict__ mv,
    const short* __restrict__ gate,
    const short* __restrict__ Ut, const short* __restrict__ Vt,
    const short* __restrict__ w1t, const float* __restrict__ b1,
    const short* __restrict__ w2t, const float* __restrict__ b2,
    float* __restrict__ ps, float* __restrict__ pv,
    short* __restrict__ abuf, int P, int first) {
    __shared__ short S0[192 * 136];
    __shared__ short S1[192 * 136];
    __shared__ short S2[192 * 136];
    const int tid = threadIdx.x;
    const int wave = tid >> 6, lane = tid & 63;
    const int l15 = lane & 15, l16 = lane >> 4;
    const int rows0 = blockIdx.x * 64;
    // P3: blend (gate from global) -> ps/pv, pvbf -> S2[192][136]
    for (int it = 0; it < 16; it++) {
        int idx = it * 512 + tid;
        int r = idx >> 7, g = idx & 127;
        int row = rows0 + r;
        if (row < P) {
            float gs = bf2f(gate[(size_t)row * 256 + g]);
            float gv = bf2f(gate[(size_t)row * 256 + 128 + g]);
            size_t o = (size_t)row * 128 + g;
            float pso = first ? 0.f : ps[o];
            ps[o] = pso * gs + (1.0f - gs) * bf2f(ms[o]);
#pragma unroll
            for (int i3 = 0; i3 < 3; i3++) {
                size_t o3 = ((size_t)row * 3 + i3) * 128 + g;
                float pvo = first ? 0.f : pv[o3];
                float val = pvo * gv + (1.0f - gv) * bf2f(mv[o3]);
                pv[o3] = val;
                S2[(3 * r + i3) * 136 + g] = f2bf(val);
            }
        } else {
#pragma unroll
            for (int i3 = 0; i3 < 3; i3++) S2[(3 * r + i3) * 136 + g] = 0;
        }
    }
    __threadfence_block();
    __syncthreads();
    // P4: Uv = pvbf@Ut -> S0; Vv = pvbf@Vt -> S1
    if (wave < 6) {
        const int chunk = wave % 3;
        const short* Bt = (wave < 3) ? Ut : Vt;
        short* dst = (wave < 3) ? S0 : S1;
#pragma unroll
        for (int half = 0; half < 2; half++) {
            f32x4 acc[4][4] = {};
            mfma_l<4>(S2, 136, chunk * 64, Bt, 128, half * 64, 128, lane, acc);
#pragma unroll
            for (int j = 0; j < 4; j++) {
                int cn = half * 64 + j * 16 + l15;
#pragma unroll
                for (int i = 0; i < 4; i++)
#pragma unroll
                    for (int r = 0; r < 4; r++)
                        dst[(chunk * 64 + i * 16 + l16 * 4 + r) * 136 + cn] = f2bf(acc[i][j][r]);
            }
        }
    }
    __syncthreads();
    // P5: cat -> S2[64][264]
    for (int it = 0; it < 16; it++) {
        int idx = it * 512 + tid;
        int r = idx >> 7, g = idx & 127;
        int row = rows0 + r;
        float sv = (row < P) ? ps[(size_t)row * 128 + g] : 0.f;
        float w0 = bf2f(S1[(3 * r + 0) * 136 + g]);
        float w1 = bf2f(S1[(3 * r + 1) * 136 + g]);
        float w2 = bf2f(S1[(3 * r + 2) * 136 + g]);
        S2[r * 264 + g] = f2bf(sv);
        S2[r * 264 + 128 + g] = f2bf(sqrtf(w0 * w0 + w1 * w1 + w2 * w2));
    }
    __syncthreads();
    // P6: h = silu(cat@w1t+b1) -> S2 + 16896
    if (wave < 2) {
        f32x4 acc[4][4] = {};
        mfma_l<4>(S2, 264, 0, w1t, 256, wave * 64, 256, lane, acc);
#pragma unroll
        for (int j = 0; j < 4; j++) {
            int cn = wave * 64 + j * 16 + l15;
            float bb = b1[cn];
#pragma unroll
            for (int i = 0; i < 4; i++)
#pragma unroll
                for (int r = 0; r < 4; r++) {
                    float v = acc[i][j][r] + bb;
                    v = v / (1.0f + expf(-v));
                    S2[16896 + (i * 16 + l16 * 4 + r) * 136 + cn] = f2bf(v);
                }
        }
    }
    __syncthreads();
    // P7: a = h@w2t+b2 -> global abuf
    if (wave < 6) {
        f32x4 acc[4][4] = {};
        mfma_l<4>(S2 + 16896, 136, 0, w2t, 128, wave * 64, 128, lane, acc);
#pragma unroll
        for (int j = 0; j < 4; j++) {
            int gn = wave * 64 + j * 16 + l15;
            float bb = b2[gn];
#pragma unroll
            for (int i = 0; i < 4; i++)
#pragma unroll
                for (int r = 0; r < 4; r++) {
                    int gm = rows0 + i * 16 + l16 * 4 + r;
                    if (gm < P) abuf[(size_t)gm * 384 + gn] = f2bf(acc[i][j][r] + bb);
                }
        }
    }
    __threadfence_block();
    __syncthreads();
    // P8: update
    for (int it = 0; it < 16; it++) {
        int idx = it * 512 + tid;
        int r = idx >> 7, g = idx & 127;
        int row = rows0 + r;
        if (row >= P) continue;
        float u0 = bf2f(S0[(3 * r + 0) * 136 + g]);
        float u1 = bf2f(S0[(3 * r + 1) * 136 + g]);
        float u2 = bf2f(S0[(3 * r + 2) * 136 + g]);
        float w0 = bf2f(S1[(3 * r + 0) * 136 + g]);
        float w1 = bf2f(S1[(3 * r + 1) * 136 + g]);
        float w2 = bf2f(S1[(3 * r + 2) * 136 + g]);
        float inner = u0 * w0 + u1 * w1 + u2 * w2;
        const short* arow = abuf + (size_t)row * 384;
        float ass = bf2f(arow[g]), asv = bf2f(arow[128 + g]), avv = bf2f(arow[256 + g]);
        size_t so = (size_t)row * 128 + g;
        ps[so] = ps[so] + ass + asv * inner;
        size_t b = (size_t)row * 384;
        pv[b + g] += avv * u0;
        pv[b + 128 + g] += avv * u1;
        pv[b + 256 + g] += avv * u2;
    }
}

// ======== gather ACC on packed 12B rows ========
#define GATHER_ACC(u, Tq, Pq)                                              \
    {                                                                      \
        const float fr = (u).w - (float)((int)(u).w);                      \
        const float a0 = blo((Tq).w0), a1 = bhi((Tq).w0), a2 = blo((Tq).w1); \
        const float f0 = fmaf(fr, bhi((Tq).w1) - a0, a0);                  \
        const float f1 = fmaf(fr, blo((Tq).w2) - a1, a1);                  \
        const float f2 = fmaf(fr, bhi((Tq).w2) - a2, a2);                  \
        const float gsv = f0 * blo((Pq).w0);                               \
        const float gev = f1 * bhi((Pq).w0);                               \
        accs += f2 * blo((Pq).w1);                                         \
        av0 = fmaf(bhi((Pq).w1), gsv, fmaf(gev, (u).x, av0));              \
        av1 = fmaf(blo((Pq).w2), gsv, fmaf(gev, (u).y, av1));              \
        av2 = fmaf(bhi((Pq).w2), gsv, fmaf(gev, (u).z, av2));              \
    }

// ---------------- gather, non-split (256 thr, 2 dests/block, 4-unroll) — probe ----------------
__global__ __launch_bounds__(256) void k_gather_ns(
    const float4* __restrict__ erec, const int* __restrict__ srcs,
    const int* __restrict__ eoff, const short* __restrict__ Tp,
    const short* __restrict__ PV,
    const float* __restrict__ s_in, const float* __restrict__ v_in,
    float* __restrict__ s_out, float* __restrict__ v_out,
    short* __restrict__ s_out_bf, short* __restrict__ v_out_bf, int ndst,
    long tzs, long pvzs, long mszs, long mvzs) {
    const int t = threadIdx.x & 127;
    const int half = threadIdx.x >> 7;
    const int z = blockIdx.z;
    const short* __restrict__ T = Tp + (size_t)z * tzs;
    const short* __restrict__ PVz = PV + (size_t)z * pvzs;
    short* __restrict__ msz = s_out_bf ? s_out_bf + (size_t)z * mszs : nullptr;
    short* __restrict__ mvz = v_out_bf ? v_out_bf + (size_t)z * mvzs : nullptr;

    for (int d = blockIdx.x * 2 + half; d < ndst; d += gridDim.x * 2) {
        const int e0 = eoff[d], e1 = eoff[d + 1];
        float accs = 0.f, av0 = 0.f, av1 = 0.f, av2 = 0.f;

        int ii = e0;
        for (; ii + 3 < e1; ii += 4) {
            const float4 u0 = erec[ii + 0], u1 = erec[ii + 1];
            const float4 u2 = erec[ii + 2], u3 = erec[ii + 3];
            const int s0 = srcs[ii + 0], s1 = srcs[ii + 1];
            const int s2 = srcs[ii + 2], s3 = srcs[ii + 3];
            const U6 T0 = *(const U6*)(T + ((size_t)(int)u0.w * 128 + t) * 6);
            const U6 T1 = *(const U6*)(T + ((size_t)(int)u1.w * 128 + t) * 6);
            const U6 T2 = *(const U6*)(T + ((size_t)(int)u2.w * 128 + t) * 6);
            const U6 T3 = *(const U6*)(T + ((size_t)(int)u3.w * 128 + t) * 6);
            const U6 P0 = *(const U6*)(PVz + ((size_t)s0 * 128 + t) * 6);
            const U6 P1 = *(const U6*)(PVz + ((size_t)s1 * 128 + t) * 6);
            const U6 P2 = *(const U6*)(PVz + ((size_t)s2 * 128 + t) * 6);
            const U6 P3 = *(const U6*)(PVz + ((size_t)s3 * 128 + t) * 6);
            GATHER_ACC(u0, T0, P0); GATHER_ACC(u1, T1, P1);
            GATHER_ACC(u2, T2, P2); GATHER_ACC(u3, T3, P3);
        }
        for (; ii < e1; ++ii) {
            const float4 u = erec[ii];
            const int s = srcs[ii];
            const U6 Tq = *(const U6*)(T + ((size_t)(int)u.w * 128 + t) * 6);
            const U6 Pq = *(const U6*)(PVz + ((size_t)s * 128 + t) * 6);
            GATHER_ACC(u, Tq, Pq);
        }

        if (s_in) {
            accs += s_in[(size_t)d * 128 + t];
            av0 += v_in[(size_t)d * 384 + t];
            av1 += v_in[(size_t)d * 384 + 128 + t];
            av2 += v_in[(size_t)d * 384 + 256 + t];
        }
        if (s_out) {
            s_out[(size_t)d * 128 + t] = accs;
            v_out[(size_t)d * 384 + t] = av0;
            v_out[(size_t)d * 384 + 128 + t] = av1;
            v_out[(size_t)d * 384 + 256 + t] = av2;
        }
        if (msz) msz[(size_t)d * 128 + t] = f2bf(accs);
        if (mvz) {
            mvz[(size_t)(3 * d + 0) * 128 + t] = f2bf(av0);
            mvz[(size_t)(3 * d + 1) * 128 + t] = f2bf(av1);
            mvz[(size_t)(3 * d + 2) * 128 + t] = f2bf(av2);
        }
    }
}

// ---------------- gather, 2-way edge split (512 thr) — atoms ----------------
__global__ __launch_bounds__(512) void k_gather_sp(
    const float4* __restrict__ erec, const int* __restrict__ srcs,
    const int* __restrict__ eoff, const short* __restrict__ Tp,
    const short* __restrict__ PV,
    const float* __restrict__ s_in, const float* __restrict__ v_in,
    float* __restrict__ s_out, float* __restrict__ v_out,
    short* __restrict__ s_out_bf, short* __restrict__ v_out_bf, int ndst,
    long tzs, long pvzs, long mszs, long mvzs) {
    __shared__ float red[2][128][4];
    const int tid = threadIdx.x;
    const int t = tid & 127;
    const int split = (tid >> 7) & 1;
    const int dsel = tid >> 8;
    const int z = blockIdx.z;
    const short* __restrict__ T = Tp + (size_t)z * tzs;
    const short* __restrict__ PVz = PV + (size_t)z * pvzs;
    short* __restrict__ msz = s_out_bf ? s_out_bf + (size_t)z * mszs : nullptr;
    short* __restrict__ mvz = v_out_bf ? v_out_bf + (size_t)z * mvzs : nullptr;

    const int d = blockIdx.x * 2 + dsel;
    const bool valid = d < ndst;
    int e0 = 0, e1 = 0;
    if (valid) { e0 = eoff[d]; e1 = eoff[d + 1]; }
    const int emid = e0 + ((e1 - e0 + 1) >> 1);
    const int lo = split ? emid : e0;
    const int hi = split ? e1 : emid;

    float accs = 0.f, av0 = 0.f, av1 = 0.f, av2 = 0.f;

    int ii = lo;
    for (; ii + 3 < hi; ii += 4) {
        const float4 u0 = erec[ii + 0], u1 = erec[ii + 1];
        const float4 u2 = erec[ii + 2], u3 = erec[ii + 3];
        const int s0 = srcs[ii + 0], s1 = srcs[ii + 1];
        const int s2 = srcs[ii + 2], s3 = srcs[ii + 3];
        const U6 T0 = *(const U6*)(T + ((size_t)(int)u0.w * 128 + t) * 6);
        const U6 T1 = *(const U6*)(T + ((size_t)(int)u1.w * 128 + t) * 6);
        const U6 T2 = *(const U6*)(T + ((size_t)(int)u2.w * 128 + t) * 6);
        const U6 T3 = *(const U6*)(T + ((size_t)(int)u3.w * 128 + t) * 6);
        const U6 P0 = *(const U6*)(PVz + ((size_t)s0 * 128 + t) * 6);
        const U6 P1 = *(const U6*)(PVz + ((size_t)s1 * 128 + t) * 6);
        const U6 P2 = *(const U6*)(PVz + ((size_t)s2 * 128 + t) * 6);
        const U6 P3 = *(const U6*)(PVz + ((size_t)s3 * 128 + t) * 6);
        GATHER_ACC(u0, T0, P0); GATHER_ACC(u1, T1, P1);
        GATHER_ACC(u2, T2, P2); GATHER_ACC(u3, T3, P3);
    }
    for (; ii < hi; ++ii) {
        const float4 u = erec[ii];
        const int s = srcs[ii];
        const U6 Tq = *(const U6*)(T + ((size_t)(int)u.w * 128 + t) * 6);
        const U6 Pq = *(const U6*)(PVz + ((size_t)s * 128 + t) * 6);
        GATHER_ACC(u, Tq, Pq);
    }

    if (split) {
        red[dsel][t][0] = accs; red[dsel][t][1] = av0;
        red[dsel][t][2] = av1;  red[dsel][t][3] = av2;
    }
    __syncthreads();
    if (!split && valid) {
        accs += red[dsel][t][0];
        av0 += red[dsel][t][1];
        av1 += red[dsel][t][2];
        av2 += red[dsel][t][3];
        if (s_in) {
            accs += s_in[(size_t)d * 128 + t];
            av0 += v_in[(size_t)d * 384 + t];
            av1 += v_in[(size_t)d * 384 + 128 + t];
            av2 += v_in[(size_t)d * 384 + 256 + t];
        }
        if (s_out) {
            s_out[(size_t)d * 128 + t] = accs;
            v_out[(size_t)d * 384 + t] = av0;
            v_out[(size_t)d * 384 + 128 + t] = av1;
            v_out[(size_t)d * 384 + 256 + t] = av2;
        }
        if (msz) msz[(size_t)d * 128 + t] = f2bf(accs);
        if (mvz) {
            mvz[(size_t)(3 * d + 0) * 128 + t] = f2bf(av0);
            mvz[(size_t)(3 * d + 1) * 128 + t] = f2bf(av1);
            mvz[(size_t)(3 * d + 2) * 128 + t] = f2bf(av2);
        }
    }
}

extern "C" void kernel_launch(void* const* d_in, const int* in_sizes, int n_in,
                              void* d_out, int out_size, void* d_ws, size_t ws_size,
                              hipStream_t stream) {
    const float* atom_xyz  = (const float*)d_in[0];
    const float* probe_xyz = (const float*)d_in[1];
    const float* cell      = (const float*)d_in[2];
    const float* a_disp    = (const float*)d_in[3];
    const float* p_disp    = (const float*)d_in[4];
    const float* atom_embed= (const float*)d_in[5];
    const float* ai_fw = (const float*)d_in[6];
    const float* ai_fb = (const float*)d_in[7];
    const float* ai_b1 = (const float*)d_in[9];
    const float* ai_b2 = (const float*)d_in[11];
    const float* au_b1 = (const float*)d_in[15];
    const float* au_b2 = (const float*)d_in[17];
    const float* pm_fw = (const float*)d_in[18];
    const float* pm_fb = (const float*)d_in[19];
    const float* pm_b1 = (const float*)d_in[21];
    const float* pm_b2 = (const float*)d_in[23];
    const float* pm_gb1= (const float*)d_in[25];
    const float* pm_gb2= (const float*)d_in[27];
    const float* pu_b1 = (const float*)d_in[31];
    const float* pu_b2 = (const float*)d_in[33];
    const int* nodes_Z = (const int*)d_in[34];
    const int* a_edges = (const int*)d_in[35];
    const int* p_edges = (const int*)d_in[36];

    const int N  = in_sizes[34];
    const int EA = in_sizes[35] / 2;
    const int EP = in_sizes[36] / 2;
    const int P  = in_sizes[1] / 3;

    enum { W_AI_W1=0, W_AI_W2, W_AU_U, W_AU_V, W_AU_W1, W_AU_W2, W_PM_W1, W_PM_W2,
           W_PM_GW1, W_PM_GW2, W_PU_U, W_PU_V, W_PU_W1, W_PU_W2 };
    const int wsrc[14] = {8,10,12,13,14,16,20,22,24,26,28,29,30,32};
    const int wK[14]   = {128,128,128,128,256,128,128,128,128,256,128,128,256,128};
    const int wN[14]   = {128,384,128,128,128,384,128,384,256,256,128,128,128,384};
    size_t woff[15]; woff[0] = 0;
    for (int i = 0; i < 14; i++) woff[i + 1] = woff[i] + (size_t)3 * wK[i] * wN[i];

    char* w = (char*)d_ws;
    size_t off = 0;
    auto alloc = [&](size_t bytes) -> void* {
        void* p = w + off;
        off = (off + bytes + 255) & ~(size_t)255;
        return p;
    };
    int* a_off  = (int*)alloc((size_t)(N + 1) * 4);
    int* a_cur  = (int*)alloc((size_t)N * 4);
    int* a_eids = (int*)alloc((size_t)EA * 4);
    int* a_srcs = (int*)alloc((size_t)EA * 4);
    int* p_off  = (int*)alloc((size_t)(P + 1) * 4);
    int* p_cur  = (int*)alloc((size_t)P * 4);
    int* p_eids = (int*)alloc((size_t)EP * 4);
    int* p_srcs = (int*)alloc((size_t)EP * 4);
    float4* a_erec = (float4*)alloc((size_t)EA * 16);
    float4* p_erec = (float4*)alloc((size_t)EP * 16);
    float* Sp   = (float*)alloc((size_t)(BINS + 1) * 32 * 4);
    float* fwp  = (float*)alloc((size_t)6 * 32 * 384 * 4);
    short* Tbf  = (short*)alloc((size_t)6 * (BINS + 1) * 512 * 2);
    short* Tp   = (short*)alloc((size_t)6 * BINS * ROWW * 2);
    short* wbt  = (short*)alloc(woff[14] * 2);
    float* s0     = (float*)alloc((size_t)N * F * 4);
    float* v0     = (float*)alloc((size_t)N * 3 * F * 4);
    float* s_list = (float*)alloc((size_t)LAYERS * N * F * 4);
    float* v_list = (float*)alloc((size_t)LAYERS * N * 3 * F * 4);
    float* msf    = (float*)alloc((size_t)N * F * 4);
    float* mvf    = (float*)alloc((size_t)N * 3 * F * 4);
    short* s0_bf    = (short*)alloc((size_t)N * F * 2);
    short* sbf_list = (short*)alloc((size_t)LAYERS * N * F * 2);
    short* vpk6     = (short*)alloc((size_t)4 * N * ROWW * 2);
    short* ms3      = (short*)alloc((size_t)3 * P * F * 2);
    short* mv3      = (short*)alloc((size_t)3 * 3 * P * F * 2);
    short* gate3    = (short*)alloc((size_t)3 * P * 256 * 2);
    short* mv_bf    = (short*)alloc((size_t)N * 3 * F * 2);
    short* abuf_bf  = (short*)alloc((size_t)P * 3 * F * 2);
    (void)ws_size; (void)n_in;

    // CSR atoms (cutoff-filtered)
    hipMemsetAsync(a_cur, 0, (size_t)N * 4, stream);
    k_count<<<(EA + 255) / 256, 256, 0, stream>>>(a_edges, atom_xyz, atom_xyz, a_disp, cell, a_cur, EA);
    k_scan<<<1, 1024, 0, stream>>>(a_cur, a_off, N);
    hipMemcpyAsync(a_cur, a_off, (size_t)N * 4, hipMemcpyDeviceToDevice, stream);
    k_scatter<<<(EA + 255) / 256, 256, 0, stream>>>(a_edges, atom_xyz, atom_xyz, a_disp, cell, a_cur, a_eids, EA);
    // CSR probes
    hipMemsetAsync(p_cur, 0, (size_t)P * 4, stream);
    k_count<<<(EP + 255) / 256, 256, 0, stream>>>(p_edges, atom_xyz, probe_xyz, p_disp, cell, p_cur, EP);
    k_scan<<<1, 1024, 0, stream>>>(p_cur, p_off, P);
    hipMemcpyAsync(p_cur, p_off, (size_t)P * 4, hipMemcpyDeviceToDevice, stream);
    k_scatter<<<(EP + 255) / 256, 256, 0, stream>>>(p_edges, atom_xyz, probe_xyz, p_disp, cell, p_cur, p_eids, EP);

    // edge records
    k_geom_rec<<<(EA + 255) / 256, 256, 0, stream>>>(atom_xyz, atom_xyz, a_disp, cell, a_edges,
                                                     a_eids, a_off, N, a_erec, a_srcs);
    k_geom_rec<<<(EP + 255) / 256, 256, 0, stream>>>(atom_xyz, probe_xyz, p_disp, cell, p_edges,
                                                     p_eids, p_off, P, p_erec, p_srcs);

    // filter tables
    k_sbuild<<<(BINS + 256) / 256, 256, 0, stream>>>(Sp);
    k_fwpack<<<(6 * 32 * 384 + 255) / 256, 256, 0, stream>>>(ai_fw, ai_fb, pm_fw, pm_fb, fwp);
    {
        dim3 g(384 / 64, (BINS + 1 + 63) / 64, 6);
        k_gemm<<<g, 256, 0, stream>>>(Sp, fwp, Tbf, BINS + 1, 384, 32, 4, 32 * 384, (BINS + 1) * 512);
    }
    k_tpack<<<(6 * BINS * 128 + 255) / 256, 256, 0, stream>>>(Tbf, Tp);

    // weights -> bf16 transposed
    {
        CvtArgs ca;
        for (int i = 0; i < 14; i++) {
            ca.src[i] = (const float*)d_in[wsrc[i]];
            ca.dstoff[i] = (int)woff[i];
            ca.Kk[i] = wK[i]; ca.Nn[i] = wN[i];
        }
        k_cvtw<<<dim3(64, 14, 3), 256, 0, stream>>>(ca, wbt);
    }
    auto wt = [&](int a, int l) { return wbt + woff[a] + (size_t)l * wK[a] * wN[a]; };

    // init node states
    k_embed<<<(N * F + 255) / 256, 256, 0, stream>>>(nodes_Z, atom_embed, s0, s0_bf, N);
    hipMemsetAsync(v0, 0, (size_t)N * 3 * F * 4, stream);
    hipMemsetAsync(vpk6, 0, (size_t)N * ROWW * 2, stream);

    auto pvbuf = [&](int idx) { return vpk6 + (size_t)idx * N * ROWW; };
    const int nb_atom32 = (N + 31) / 32;
    const int nb_probe64 = (P + 63) / 64;

    // ---- atom message-passing layers ----
    for (int l = 0; l < LAYERS; l++) {
        const float* scur = l ? (s_list + (size_t)(l - 1) * N * F) : s0;
        const float* vcur = l ? (v_list + (size_t)(l - 1) * N * 3 * F) : v0;
        const short* scur_bf = l ? (sbf_list + (size_t)(l - 1) * N * F) : s0_bf;
        k_mlp2<<<dim3(nb_atom32, 1, 1), 512, 0, stream>>>(
            scur_bf, wt(W_AI_W1, l), ai_b1 + (size_t)l * F,
            wt(W_AI_W2, l), ai_b2 + (size_t)l * 3 * F,
            pvbuf(l), N, 0, 0, 0, 0, 0, 0);
        k_gather_sp<<<dim3((N + 1) / 2, 1, 1), 512, 0, stream>>>(a_erec, a_srcs, a_off,
                 Tp + (size_t)l * BINS * ROWW, pvbuf(l),
                 scur, vcur, msf, mvf, nullptr, mv_bf, N, 0, 0, 0, 0);
        k_paiupd<<<dim3(nb_atom32), 512, 0, stream>>>(
            mv_bf, msf, mvf,
            wt(W_AU_U, l), wt(W_AU_V, l),
            wt(W_AU_W1, l), au_b1 + (size_t)l * F,
            wt(W_AU_W2, l), au_b2 + (size_t)l * 3 * F,
            s_list + (size_t)l * N * F, v_list + (size_t)l * N * 3 * F,
            sbf_list + (size_t)l * N * F, pvbuf(l + 1), abuf_bf, N);
    }

    // ---- probe phase ----
    float* ps = (float*)d_out;
    float* pv = (float*)d_out + (size_t)P * F;

    // batched probe phi (all 3 layers) -> pvbuf(1..3) slots 0-2
    k_mlp2<<<dim3(nb_atom32, 1, 3), 512, 0, stream>>>(
        sbf_list, wt(W_PM_W1, 0), pm_b1, wt(W_PM_W2, 0), pm_b2,
        pvbuf(1), N,
        (long)N * F, (long)128 * 128, 128, (long)128 * 384, 384, (long)N * ROWW);

    // fused 3-layer probe gather
    k_gather_ns<<<dim3((P + 1) / 2, 1, 3), 256, 0, stream>>>(p_erec, p_srcs, p_off,
             Tp + (size_t)3 * BINS * ROWW, pvbuf(1),
             nullptr, nullptr, nullptr, nullptr, ms3, mv3, P,
             (long)BINS * ROWW, (long)N * ROWW, (long)P * F, (long)3 * P * F);

    // batched probe gates (all 3 layers): depend only on ms3
    k_gate3<<<dim3(nb_probe64, 1, 3), 256, 0, stream>>>(
        ms3, wt(W_PM_GW1, 0), pm_gb1, wt(W_PM_GW2, 0), pm_gb2, gate3, P,
        (long)P * F, (long)128 * 256, 256, (long)256 * 256, 256, (long)P * 256);

    for (int l = 0; l < LAYERS; l++) {
        k_probe_layer<<<dim3(nb_probe64), 512, 0, stream>>>(
            ms3 + (size_t)l * P * F, mv3 + (size_t)l * 3 * P * F,
            gate3 + (size_t)l * P * 256,
            wt(W_PU_U, l), wt(W_PU_V, l),
            wt(W_PU_W1, l), pu_b1 + (size_t)l * F,
            wt(W_PU_W2, l), pu_b2 + (size_t)l * 3 * F,
            ps, pv, abuf_bf, P, l == 0);
    }
}